// Round 13
// baseline (351.537 us; speedup 1.0000x reference)
//
#include <hip/hip_runtime.h>
#include <cmath>

#define NN    4096
#define FIN   32
#define KSEL  39      // neighbors kept (top-40 minus self)
#define PP    22
#define PPAD  24
#define FOUT  48
#define WPB   2       // waves per block
#define QW    4       // queries per wave
#define CAP   128     // candidate cap per query (fallback if exceeded)

typedef float v2f __attribute__((ext_vector_type(2)));

#define WSYNC() asm volatile("s_waitcnt lgkmcnt(0)" ::: "memory")

__device__ __forceinline__ v2f sp2(float f) { v2f r = {f, f}; return r; }

// ---------------- precompute: one thread per point -------------------------------
// coords in element layout (query constants, tail) AND pair-SoA layout
// [x0,x1,y0,y1,z0,z1,w0,w1] (packed scan).
__global__ __launch_bounds__(256) void gn_pre(
    const float* __restrict__ x,
    const float* __restrict__ Wf, const float* __restrict__ bf,
    const float* __restrict__ Ws, const float* __restrict__ bs,
    float* __restrict__ coords4, float* __restrict__ cpair, float* __restrict__ feats)
{
    int p = blockIdx.x * 256 + threadIdx.x;

    const float4* xr4 = (const float4*)(x + (size_t)p * FIN);
    float xv[FIN];
    #pragma unroll
    for (int i = 0; i < 8; ++i) {
        float4 t = xr4[i];
        xv[4*i] = t.x; xv[4*i+1] = t.y; xv[4*i+2] = t.z; xv[4*i+3] = t.w;
    }

    float fa[PP];
    #pragma unroll
    for (int c = 0; c < PP; ++c) fa[c] = bf[c];
    #pragma unroll
    for (int i = 0; i < FIN; ++i) {
        float xi = xv[i];
        #pragma unroll
        for (int c = 0; c < PP; ++c) fa[c] = fmaf(xi, Wf[i * PP + c], fa[c]);
    }

    float ca[4];
    #pragma unroll
    for (int c = 0; c < 4; ++c) ca[c] = bs[c];
    #pragma unroll
    for (int i = 0; i < FIN; ++i) {
        float xi = xv[i];
        #pragma unroll
        for (int c = 0; c < 4; ++c) ca[c] = fmaf(xi, Ws[i * 4 + c], ca[c]);
    }

    float4* fw = (float4*)(feats + (size_t)p * PPAD);
    fw[0] = make_float4(fa[0],  fa[1],  fa[2],  fa[3]);
    fw[1] = make_float4(fa[4],  fa[5],  fa[6],  fa[7]);
    fw[2] = make_float4(fa[8],  fa[9],  fa[10], fa[11]);
    fw[3] = make_float4(fa[12], fa[13], fa[14], fa[15]);
    fw[4] = make_float4(fa[16], fa[17], fa[18], fa[19]);
    fw[5] = make_float4(fa[20], fa[21], 0.f, 0.f);

    ((float4*)coords4)[p] = make_float4(ca[0], ca[1], ca[2], ca[3]);

    int pr = p >> 1, sl = p & 1;
    float* cp = cpair + (size_t)pr * 8 + sl;
    cp[0] = ca[0]; cp[2] = ca[1]; cp[4] = ca[2]; cp[6] = ca[3];
}

// ---- fallback-only helpers (degenerate C > CAP path) ----------------------------
__device__ __forceinline__ void sort64_pair(float& v, int& m, int lane) {
    #pragma unroll
    for (int k = 2; k <= 64; k <<= 1) {
        #pragma unroll
        for (int j = k >> 1; j >= 1; j >>= 1) {
            float ov = __shfl_xor(v, j);
            int   om = __shfl_xor(m, j);
            bool keepMin = (((lane & j) == 0) == ((lane & k) == 0));
            bool less = (ov < v) || (ov == v && om < m);
            bool take = (less == keepMin);
            v = take ? ov : v;
            m = take ? om : m;
        }
    }
}
__device__ __forceinline__ void merge64(float& Lv, int& Lm, float cv, int cm, int lane) {
    float rv = __shfl_xor(cv, 63);
    int   rm = __shfl_xor(cm, 63);
    bool less = (rv < Lv) || (rv == Lv && rm < Lm);
    if (less) { Lv = rv; Lm = rm; }
    #pragma unroll
    for (int j = 32; j >= 1; j >>= 1) {
        float ov = __shfl_xor(Lv, j);
        int   om = __shfl_xor(Lm, j);
        bool lower = ((lane & j) == 0);
        bool l2 = (ov < Lv) || (ov == Lv && om < Lm);
        bool take = (l2 == lower);
        Lv = take ? ov : Lv;
        Lm = take ? om : Lm;
    }
}

// ---------------- per-query tail: selection + stage + aggregate + epilogue -------
// ALL state is scalar. Called 4 times explicitly (runtime-indexed private arrays
// demote to scratch: R9/R10's 30x HBM regression).
__device__ __forceinline__ void tail_query(
    int lane, int b, int nj, int qj, int C,
    const unsigned short* __restrict__ selq,
    const float4* __restrict__ c4, const float* __restrict__ feats,
    const float* __restrict__ x, const float* __restrict__ Wo,
    const float* __restrict__ bo,
    float* __restrict__ fstage, float* __restrict__ agg,
    unsigned* __restrict__ cnt2, float* __restrict__ out)
{
    const float INF = __builtin_inff();
    const float NEGINF = -INF;
    float4 cqj = c4[nj];
    float sqnj = fmaf(cqj.x, cqj.x, fmaf(cqj.y, cqj.y, fmaf(cqj.z, cqj.z, cqj.w * cqj.w)));

    if (lane == 0) *cnt2 = 0;
    WSYNC();

    if (C <= CAP) {
        unsigned kd0 = 0xFFFFFFFFu, ki0 = 0xFFFFFFFFu; float dv0 = 0.f;
        if (lane < C) {
            unsigned idx = (unsigned)selq[lane];
            float4 cm = c4[idx];
            float s2 = fmaf(cm.x, cm.x, fmaf(cm.y, cm.y, fmaf(cm.z, cm.z, cm.w * cm.w)));
            float dt = fmaf(cqj.x, cm.x, fmaf(cqj.y, cm.y, fmaf(cqj.z, cm.z, cqj.w * cm.w)));
            float d  = fmaxf(fmaf(-2.f, dt, s2 + sqnj), 0.f);
            dv0 = d; kd0 = __float_as_uint(d); ki0 = idx;
        }
        unsigned kd1 = 0xFFFFFFFFu, ki1 = 0xFFFFFFFFu; float dv1 = 0.f;
        if (64 + lane < C) {
            unsigned idx = (unsigned)selq[64 + lane];
            float4 cm = c4[idx];
            float s2 = fmaf(cm.x, cm.x, fmaf(cm.y, cm.y, fmaf(cm.z, cm.z, cm.w * cm.w)));
            float dt = fmaf(cqj.x, cm.x, fmaf(cqj.y, cm.y, fmaf(cqj.z, cm.z, cqj.w * cm.w)));
            float d  = fmaxf(fmaf(-2.f, dt, s2 + sqnj), 0.f);
            dv1 = d; kd1 = __float_as_uint(d); ki1 = idx;
        }
        // D = exact 39th-smallest clamped d2 bits (must stay exact)
        unsigned D = 0;
        for (int bit = 30; bit >= 0; --bit) {
            unsigned t = D | (1u << bit);
            int c = (int)__popcll(__ballot(kd0 < t))
                  + (int)__popcll(__ballot(kd1 < t));
            if (c < KSEL) D = t;
        }
        int cless  = (int)__popcll(__ballot(kd0 < D))
                   + (int)__popcll(__ballot(kd1 < D));
        int tiecnt = (int)__popcll(__ballot(kd0 == D))
                   + (int)__popcll(__ballot(kd1 == D));
        int tneed = KSEL - cless;
        unsigned TI = 0xFFFFFFFFu;
        if (tiecnt > tneed) {            // rare: resolve ties by lowest index
            unsigned pi = 0;
            for (int bit = 11; bit >= 0; --bit) {
                unsigned t = pi | (1u << bit);
                int c = (int)__popcll(__ballot((kd0 == D) && (ki0 < t)))
                      + (int)__popcll(__ballot((kd1 == D) && (ki1 < t)));
                if (c < tneed) pi = t;
            }
            TI = pi;
        }
        // stage the exactly-39 selected neighbors
        bool take0 = (kd0 < D) || ((kd0 == D) && (ki0 <= TI));
        if (take0) {
            unsigned slot = atomicAdd(cnt2, 1u);
            float wgt = __expf(-10.f * dv0);
            const float4* fr = (const float4*)(feats + ((size_t)b * NN + ki0) * PPAD);
            float4 f0 = fr[0], f1 = fr[1], f2 = fr[2], f3 = fr[3], f4 = fr[4], f5 = fr[5];
            float4* row = (float4*)(fstage + slot * PPAD);
            row[0] = make_float4(f0.x * wgt, f0.y * wgt, f0.z * wgt, f0.w * wgt);
            row[1] = make_float4(f1.x * wgt, f1.y * wgt, f1.z * wgt, f1.w * wgt);
            row[2] = make_float4(f2.x * wgt, f2.y * wgt, f2.z * wgt, f2.w * wgt);
            row[3] = make_float4(f3.x * wgt, f3.y * wgt, f3.z * wgt, f3.w * wgt);
            row[4] = make_float4(f4.x * wgt, f4.y * wgt, f4.z * wgt, f4.w * wgt);
            row[5] = make_float4(f5.x * wgt, f5.y * wgt, f5.z * wgt, f5.w * wgt);
        }
        bool take1 = (kd1 < D) || ((kd1 == D) && (ki1 <= TI));
        if (take1) {
            unsigned slot = atomicAdd(cnt2, 1u);
            float wgt = __expf(-10.f * dv1);
            const float4* fr = (const float4*)(feats + ((size_t)b * NN + ki1) * PPAD);
            float4 f0 = fr[0], f1 = fr[1], f2 = fr[2], f3 = fr[3], f4 = fr[4], f5 = fr[5];
            float4* row = (float4*)(fstage + slot * PPAD);
            row[0] = make_float4(f0.x * wgt, f0.y * wgt, f0.z * wgt, f0.w * wgt);
            row[1] = make_float4(f1.x * wgt, f1.y * wgt, f1.z * wgt, f1.w * wgt);
            row[2] = make_float4(f2.x * wgt, f2.y * wgt, f2.z * wgt, f2.w * wgt);
            row[3] = make_float4(f3.x * wgt, f3.y * wgt, f3.z * wgt, f3.w * wgt);
            row[4] = make_float4(f4.x * wgt, f4.y * wgt, f4.z * wgt, f4.w * wgt);
            row[5] = make_float4(f5.x * wgt, f5.y * wgt, f5.z * wgt, f5.w * wgt);
        }
    } else {
        // degenerate fallback: exact streaming top-64 over all 4096
        float Lv = INF; int Lm = 0x7FFFFFFF;
        for (int c = 0; c < 64; ++c) {
            int m = c * 64 + lane;
            float4 cm = c4[m];
            float s2 = fmaf(cm.x, cm.x, fmaf(cm.y, cm.y, fmaf(cm.z, cm.z, cm.w * cm.w)));
            float dt = fmaf(cqj.x, cm.x, fmaf(cqj.y, cm.y, fmaf(cqj.z, cm.z, cqj.w * cm.w)));
            float v  = fmaxf(fmaf(-2.f, dt, s2 + sqnj), 0.f);
            if (m == nj) v = INF;
            sort64_pair(v, m, lane);
            if (c == 0) { Lv = v; Lm = m; }
            else        merge64(Lv, Lm, v, m, lane);
        }
        if (lane < KSEL) {
            float wgt = __expf(-10.f * Lv);
            const float4* fr = (const float4*)(feats + ((size_t)b * NN + Lm) * PPAD);
            float4 f0 = fr[0], f1 = fr[1], f2 = fr[2], f3 = fr[3], f4 = fr[4], f5 = fr[5];
            float4* row = (float4*)(fstage + lane * PPAD);
            row[0] = make_float4(f0.x * wgt, f0.y * wgt, f0.z * wgt, f0.w * wgt);
            row[1] = make_float4(f1.x * wgt, f1.y * wgt, f1.z * wgt, f1.w * wgt);
            row[2] = make_float4(f2.x * wgt, f2.y * wgt, f2.z * wgt, f2.w * wgt);
            row[3] = make_float4(f3.x * wgt, f3.y * wgt, f3.z * wgt, f3.w * wgt);
            row[4] = make_float4(f4.x * wgt, f4.y * wgt, f4.z * wgt, f4.w * wgt);
            row[5] = make_float4(f5.x * wgt, f5.y * wgt, f5.z * wgt, f5.w * wgt);
        }
    }
    WSYNC();

    // ---- max / mean over 39 neighbors: 44 lanes, split-k ----
    if (lane < 2 * PP) {
        int g  = (lane >= PP) ? 1 : 0;
        int c  = lane - g * PP;
        int k0 = g ? 20 : 0;
        int k1 = g ? KSEL : 20;
        float mx = NEGINF, sm = 0.f;
        for (int k = k0; k < k1; ++k) {
            float v = fstage[k * PPAD + c];
            mx = fmaxf(mx, v);
            sm += v;
        }
        float mx2 = __shfl(mx, lane + PP);
        float sm2 = __shfl(sm, lane + PP);
        if (lane < PP) {
            agg[c]      = fmaxf(mx, mx2);
            agg[PP + c] = (sm + sm2) * (1.f / (float)KSEL);
        }
    }
    WSYNC();

    // ---- epilogue: out = tanh([x | max | mean] @ Wo + bo), fast tanh ----
    if (lane < FOUT) {
        const float* xr = x + (size_t)qj * FIN;
        float acc = bo[lane];
        #pragma unroll
        for (int f = 0; f < FIN; ++f)
            acc = fmaf(xr[f], Wo[f * FOUT + lane], acc);
        #pragma unroll
        for (int f = 0; f < 2 * PP; ++f)
            acc = fmaf(agg[f], Wo[(FIN + f) * FOUT + lane], acc);
        float e = __expf(2.f * acc);
        float r = __builtin_amdgcn_rcpf(e + 1.f);
        out[(size_t)qj * FOUT + lane] = fmaf(-2.f, r, 1.f);
    }
    WSYNC();
}

// ---------------- main: one wave per FOUR queries, packed-fp32 scans -------------
__global__ __launch_bounds__(WPB * 64, 8) void gn_main(
    const float* __restrict__ x,
    const float* __restrict__ Wo, const float* __restrict__ bo,
    const float* __restrict__ coords4, const float* __restrict__ cpair,
    const float* __restrict__ feats,
    float* __restrict__ out)
{
    __shared__ unsigned short sel_s[WPB * QW * CAP];     // candidate indices
    __shared__ float fstage_s[WPB * KSEL * PPAD];
    __shared__ float agg_s[WPB * 48];
    __shared__ unsigned cnt_s[WPB * QW];
    __shared__ unsigned cnt2_s[WPB];

    const float INF = __builtin_inff();
    const int wv    = threadIdx.x >> 6;
    const int lane  = threadIdx.x & 63;
    const int qbase = (blockIdx.x * WPB + wv) * QW;      // 4 queries, same batch
    const int b     = qbase >> 12;
    const int n0    = qbase & (NN - 1);
    unsigned short* selp = sel_s + wv * QW * CAP;
    float* fstage = fstage_s + wv * (KSEL * PPAD);
    float* agg    = agg_s + wv * 48;

    const float4* c4  = ((const float4*)coords4) + (size_t)b * NN;
    const float4* cp4 = ((const float4*)cpair) + (size_t)b * NN;   // NN float4 per batch

    // per-query constants -- individual scalars / fixed v2f splats only
    float4 cq0 = c4[n0 + 0], cq1 = c4[n0 + 1], cq2 = c4[n0 + 2], cq3 = c4[n0 + 3];
    float sq0 = fmaf(cq0.x, cq0.x, fmaf(cq0.y, cq0.y, fmaf(cq0.z, cq0.z, cq0.w * cq0.w)));
    float sq1 = fmaf(cq1.x, cq1.x, fmaf(cq1.y, cq1.y, fmaf(cq1.z, cq1.z, cq1.w * cq1.w)));
    float sq2 = fmaf(cq2.x, cq2.x, fmaf(cq2.y, cq2.y, fmaf(cq2.z, cq2.z, cq2.w * cq2.w)));
    float sq3 = fmaf(cq3.x, cq3.x, fmaf(cq3.y, cq3.y, fmaf(cq3.z, cq3.z, cq3.w * cq3.w)));

    if (lane < QW) cnt_s[wv * QW + lane] = 0;

    // ---- pass 1: packed 2-elem d2, per-query packed running min (self incl) ----
    v2f km0 = {INF, INF}, km1 = {INF, INF}, km2 = {INF, INF}, km3 = {INF, INF};
    #pragma unroll 4
    for (int i = 0; i < 32; ++i) {
        int pr = i * 64 + lane;
        float4 A  = cp4[2 * pr];         // x0,x1,y0,y1
        float4 Bv = cp4[2 * pr + 1];     // z0,z1,w0,w1
        v2f xs = {A.x,  A.y},  ys = {A.z,  A.w};
        v2f zs = {Bv.x, Bv.y}, ws = {Bv.z, Bv.w};
        v2f s2 = xs * xs;
        s2 = __builtin_elementwise_fma(ys, ys, s2);
        s2 = __builtin_elementwise_fma(zs, zs, s2);
        s2 = __builtin_elementwise_fma(ws, ws, s2);
        v2f dt0 = __builtin_elementwise_fma(xs, sp2(cq0.x), sp2(0.f));
        dt0 = __builtin_elementwise_fma(ys, sp2(cq0.y), dt0);
        dt0 = __builtin_elementwise_fma(zs, sp2(cq0.z), dt0);
        dt0 = __builtin_elementwise_fma(ws, sp2(cq0.w), dt0);
        v2f dt1 = __builtin_elementwise_fma(xs, sp2(cq1.x), sp2(0.f));
        dt1 = __builtin_elementwise_fma(ys, sp2(cq1.y), dt1);
        dt1 = __builtin_elementwise_fma(zs, sp2(cq1.z), dt1);
        dt1 = __builtin_elementwise_fma(ws, sp2(cq1.w), dt1);
        v2f dt2 = __builtin_elementwise_fma(xs, sp2(cq2.x), sp2(0.f));
        dt2 = __builtin_elementwise_fma(ys, sp2(cq2.y), dt2);
        dt2 = __builtin_elementwise_fma(zs, sp2(cq2.z), dt2);
        dt2 = __builtin_elementwise_fma(ws, sp2(cq2.w), dt2);
        v2f dt3 = __builtin_elementwise_fma(xs, sp2(cq3.x), sp2(0.f));
        dt3 = __builtin_elementwise_fma(ys, sp2(cq3.y), dt3);
        dt3 = __builtin_elementwise_fma(zs, sp2(cq3.z), dt3);
        dt3 = __builtin_elementwise_fma(ws, sp2(cq3.w), dt3);
        v2f d0 = __builtin_elementwise_fma(sp2(-2.f), dt0, s2 + sp2(sq0));
        v2f d1 = __builtin_elementwise_fma(sp2(-2.f), dt1, s2 + sp2(sq1));
        v2f d2 = __builtin_elementwise_fma(sp2(-2.f), dt2, s2 + sp2(sq2));
        v2f d3 = __builtin_elementwise_fma(sp2(-2.f), dt3, s2 + sp2(sq3));
        km0 = __builtin_elementwise_min(km0, d0);
        km1 = __builtin_elementwise_min(km1, d1);
        km2 = __builtin_elementwise_min(km2, d2);
        km3 = __builtin_elementwise_min(km3, d3);
    }
    unsigned kb0 = __float_as_uint(fmaxf(fminf(km0.x, km0.y), 0.f));
    unsigned kb1 = __float_as_uint(fmaxf(fminf(km1.x, km1.y), 0.f));
    unsigned kb2 = __float_as_uint(fmaxf(fminf(km2.x, km2.y), 0.f));
    unsigned kb3 = __float_as_uint(fmaxf(fminf(km3.x, km3.y), 0.f));

    // ---- bounds: 40th-smallest lane-min per query, TRUNCATED radix (bits 30..15)
    //      then widen low bits: UB' = p + 2^15 - 1 >= exact 40th value (superset).
    unsigned ub0 = 0, ub1 = 0, ub2 = 0, ub3 = 0;
    for (int bit = 30; bit >= 15; --bit) {
        unsigned msk = 1u << bit;
        unsigned t0 = ub0 | msk, t1 = ub1 | msk, t2 = ub2 | msk, t3 = ub3 | msk;
        if ((int)__popcll(__ballot(kb0 < t0)) < KSEL + 1) ub0 = t0;
        if ((int)__popcll(__ballot(kb1 < t1)) < KSEL + 1) ub1 = t1;
        if ((int)__popcll(__ballot(kb2 < t2)) < KSEL + 1) ub2 = t2;
        if ((int)__popcll(__ballot(kb3 < t3)) < KSEL + 1) ub3 = t3;
    }
    float UB0 = __uint_as_float(ub0 | 0x7FFFu);
    float UB1 = __uint_as_float(ub1 | 0x7FFFu);
    float UB2 = __uint_as_float(ub2 | 0x7FFFu);
    float UB3 = __uint_as_float(ub3 | 0x7FFFu);
    WSYNC();   // cnt init visible

    // ---- compact pass: packed d2 (same formula as pass 1), scalar predicates ----
    #pragma unroll 4
    for (int i = 0; i < 32; ++i) {
        int pr = i * 64 + lane;
        int m0 = 2 * pr, m1 = 2 * pr + 1;
        float4 A  = cp4[2 * pr];
        float4 Bv = cp4[2 * pr + 1];
        v2f xs = {A.x,  A.y},  ys = {A.z,  A.w};
        v2f zs = {Bv.x, Bv.y}, ws = {Bv.z, Bv.w};
        v2f s2 = xs * xs;
        s2 = __builtin_elementwise_fma(ys, ys, s2);
        s2 = __builtin_elementwise_fma(zs, zs, s2);
        s2 = __builtin_elementwise_fma(ws, ws, s2);
        v2f dt0 = __builtin_elementwise_fma(xs, sp2(cq0.x), sp2(0.f));
        dt0 = __builtin_elementwise_fma(ys, sp2(cq0.y), dt0);
        dt0 = __builtin_elementwise_fma(zs, sp2(cq0.z), dt0);
        dt0 = __builtin_elementwise_fma(ws, sp2(cq0.w), dt0);
        v2f dt1 = __builtin_elementwise_fma(xs, sp2(cq1.x), sp2(0.f));
        dt1 = __builtin_elementwise_fma(ys, sp2(cq1.y), dt1);
        dt1 = __builtin_elementwise_fma(zs, sp2(cq1.z), dt1);
        dt1 = __builtin_elementwise_fma(ws, sp2(cq1.w), dt1);
        v2f dt2 = __builtin_elementwise_fma(xs, sp2(cq2.x), sp2(0.f));
        dt2 = __builtin_elementwise_fma(ys, sp2(cq2.y), dt2);
        dt2 = __builtin_elementwise_fma(zs, sp2(cq2.z), dt2);
        dt2 = __builtin_elementwise_fma(ws, sp2(cq2.w), dt2);
        v2f dt3 = __builtin_elementwise_fma(xs, sp2(cq3.x), sp2(0.f));
        dt3 = __builtin_elementwise_fma(ys, sp2(cq3.y), dt3);
        dt3 = __builtin_elementwise_fma(zs, sp2(cq3.z), dt3);
        dt3 = __builtin_elementwise_fma(ws, sp2(cq3.w), dt3);
        v2f d0 = __builtin_elementwise_fma(sp2(-2.f), dt0, s2 + sp2(sq0));
        v2f d1 = __builtin_elementwise_fma(sp2(-2.f), dt1, s2 + sp2(sq1));
        v2f d2 = __builtin_elementwise_fma(sp2(-2.f), dt2, s2 + sp2(sq2));
        v2f d3 = __builtin_elementwise_fma(sp2(-2.f), dt3, s2 + sp2(sq3));
        if ((d0.x <= UB0) && (m0 != n0 + 0)) {
            unsigned s = atomicAdd(&cnt_s[wv * QW + 0], 1u);
            if (s < CAP) selp[0 * CAP + s] = (unsigned short)m0;
        }
        if ((d0.y <= UB0) && (m1 != n0 + 0)) {
            unsigned s = atomicAdd(&cnt_s[wv * QW + 0], 1u);
            if (s < CAP) selp[0 * CAP + s] = (unsigned short)m1;
        }
        if ((d1.x <= UB1) && (m0 != n0 + 1)) {
            unsigned s = atomicAdd(&cnt_s[wv * QW + 1], 1u);
            if (s < CAP) selp[1 * CAP + s] = (unsigned short)m0;
        }
        if ((d1.y <= UB1) && (m1 != n0 + 1)) {
            unsigned s = atomicAdd(&cnt_s[wv * QW + 1], 1u);
            if (s < CAP) selp[1 * CAP + s] = (unsigned short)m1;
        }
        if ((d2.x <= UB2) && (m0 != n0 + 2)) {
            unsigned s = atomicAdd(&cnt_s[wv * QW + 2], 1u);
            if (s < CAP) selp[2 * CAP + s] = (unsigned short)m0;
        }
        if ((d2.y <= UB2) && (m1 != n0 + 2)) {
            unsigned s = atomicAdd(&cnt_s[wv * QW + 2], 1u);
            if (s < CAP) selp[2 * CAP + s] = (unsigned short)m1;
        }
        if ((d3.x <= UB3) && (m0 != n0 + 3)) {
            unsigned s = atomicAdd(&cnt_s[wv * QW + 3], 1u);
            if (s < CAP) selp[3 * CAP + s] = (unsigned short)m0;
        }
        if ((d3.y <= UB3) && (m1 != n0 + 3)) {
            unsigned s = atomicAdd(&cnt_s[wv * QW + 3], 1u);
            if (s < CAP) selp[3 * CAP + s] = (unsigned short)m1;
        }
    }
    WSYNC();

    // ---- four explicit tail calls (no runtime-indexed private state) ----
    tail_query(lane, b, n0 + 0, qbase + 0, (int)cnt_s[wv * QW + 0], selp + 0 * CAP,
               c4, feats, x, Wo, bo, fstage, agg, &cnt2_s[wv], out);
    tail_query(lane, b, n0 + 1, qbase + 1, (int)cnt_s[wv * QW + 1], selp + 1 * CAP,
               c4, feats, x, Wo, bo, fstage, agg, &cnt2_s[wv], out);
    tail_query(lane, b, n0 + 2, qbase + 2, (int)cnt_s[wv * QW + 2], selp + 2 * CAP,
               c4, feats, x, Wo, bo, fstage, agg, &cnt2_s[wv], out);
    tail_query(lane, b, n0 + 3, qbase + 3, (int)cnt_s[wv * QW + 3], selp + 3 * CAP,
               c4, feats, x, Wo, bo, fstage, agg, &cnt2_s[wv], out);
}

extern "C" void kernel_launch(void* const* d_in, const int* in_sizes, int n_in,
                              void* d_out, int out_size, void* d_ws, size_t ws_size,
                              hipStream_t stream) {
    const float* x  = (const float*)d_in[0];
    const float* Wf = (const float*)d_in[1];
    const float* bf = (const float*)d_in[2];
    const float* Ws = (const float*)d_in[3];
    const float* bs = (const float*)d_in[4];
    const float* Wo = (const float*)d_in[5];
    const float* bo = (const float*)d_in[6];
    float* outp = (float*)d_out;

    float* ws      = (float*)d_ws;
    float* coords4 = ws;                      // 32768*4  = 131072 floats
    float* cpair   = ws + 131072;             // 32768*4  = 131072 floats (pair-SoA)
    float* feats   = ws + 262144;             // 32768*24 = 786432 floats

    gn_pre<<<32768 / 256, 256, 0, stream>>>(x, Wf, bf, Ws, bs, coords4, cpair, feats);
    gn_main<<<32768 / (WPB * QW), WPB * 64, 0, stream>>>(x, Wo, bo, coords4, cpair, feats, outp);
}

// Round 14
// 239.018 us; speedup vs baseline: 1.4708x; 1.4708x over previous
//
#include <hip/hip_runtime.h>
#include <cmath>

#define NN    4096
#define FIN   32
#define KSEL  39      // neighbors kept (top-40 minus self)
#define PP    22
#define PPAD  24
#define FOUT  48
#define WPB   2       // waves per block
#define QW    4       // queries per wave
#define CAP   128     // candidate cap per query (fallback if exceeded)

typedef float v2f __attribute__((ext_vector_type(2)));

#define WSYNC() asm volatile("s_waitcnt lgkmcnt(0)" ::: "memory")

__device__ __forceinline__ v2f sp2(float f) { v2f r = {f, f}; return r; }

// ---------------- precompute: one thread per point -------------------------------
// coords in element layout (query constants, tail) AND pair-SoA layout
// [x0,x1,y0,y1,z0,z1,w0,w1] (packed scan).
__global__ __launch_bounds__(256) void gn_pre(
    const float* __restrict__ x,
    const float* __restrict__ Wf, const float* __restrict__ bf,
    const float* __restrict__ Ws, const float* __restrict__ bs,
    float* __restrict__ coords4, float* __restrict__ cpair, float* __restrict__ feats)
{
    int p = blockIdx.x * 256 + threadIdx.x;

    const float4* xr4 = (const float4*)(x + (size_t)p * FIN);
    float xv[FIN];
    #pragma unroll
    for (int i = 0; i < 8; ++i) {
        float4 t = xr4[i];
        xv[4*i] = t.x; xv[4*i+1] = t.y; xv[4*i+2] = t.z; xv[4*i+3] = t.w;
    }

    float fa[PP];
    #pragma unroll
    for (int c = 0; c < PP; ++c) fa[c] = bf[c];
    #pragma unroll
    for (int i = 0; i < FIN; ++i) {
        float xi = xv[i];
        #pragma unroll
        for (int c = 0; c < PP; ++c) fa[c] = fmaf(xi, Wf[i * PP + c], fa[c]);
    }

    float ca[4];
    #pragma unroll
    for (int c = 0; c < 4; ++c) ca[c] = bs[c];
    #pragma unroll
    for (int i = 0; i < FIN; ++i) {
        float xi = xv[i];
        #pragma unroll
        for (int c = 0; c < 4; ++c) ca[c] = fmaf(xi, Ws[i * 4 + c], ca[c]);
    }

    float4* fw = (float4*)(feats + (size_t)p * PPAD);
    fw[0] = make_float4(fa[0],  fa[1],  fa[2],  fa[3]);
    fw[1] = make_float4(fa[4],  fa[5],  fa[6],  fa[7]);
    fw[2] = make_float4(fa[8],  fa[9],  fa[10], fa[11]);
    fw[3] = make_float4(fa[12], fa[13], fa[14], fa[15]);
    fw[4] = make_float4(fa[16], fa[17], fa[18], fa[19]);
    fw[5] = make_float4(fa[20], fa[21], 0.f, 0.f);

    ((float4*)coords4)[p] = make_float4(ca[0], ca[1], ca[2], ca[3]);

    int pr = p >> 1, sl = p & 1;
    float* cp = cpair + (size_t)pr * 8 + sl;
    cp[0] = ca[0]; cp[2] = ca[1]; cp[4] = ca[2]; cp[6] = ca[3];
}

// ---- fallback-only helpers (degenerate C > CAP path) ----------------------------
__device__ __forceinline__ void sort64_pair(float& v, int& m, int lane) {
    #pragma unroll
    for (int k = 2; k <= 64; k <<= 1) {
        #pragma unroll
        for (int j = k >> 1; j >= 1; j >>= 1) {
            float ov = __shfl_xor(v, j);
            int   om = __shfl_xor(m, j);
            bool keepMin = (((lane & j) == 0) == ((lane & k) == 0));
            bool less = (ov < v) || (ov == v && om < m);
            bool take = (less == keepMin);
            v = take ? ov : v;
            m = take ? om : m;
        }
    }
}
__device__ __forceinline__ void merge64(float& Lv, int& Lm, float cv, int cm, int lane) {
    float rv = __shfl_xor(cv, 63);
    int   rm = __shfl_xor(cm, 63);
    bool less = (rv < Lv) || (rv == Lv && rm < Lm);
    if (less) { Lv = rv; Lm = rm; }
    #pragma unroll
    for (int j = 32; j >= 1; j >>= 1) {
        float ov = __shfl_xor(Lv, j);
        int   om = __shfl_xor(Lm, j);
        bool lower = ((lane & j) == 0);
        bool l2 = (ov < Lv) || (ov == Lv && om < Lm);
        bool take = (l2 == lower);
        Lv = take ? ov : Lv;
        Lm = take ? om : Lm;
    }
}

// ---------------- per-query tail: selection + stage + aggregate + epilogue -------
// ALL state is scalar. Called 4 times explicitly (runtime-indexed private arrays
// demote to scratch: R9/R10's 30x HBM regression).
__device__ __forceinline__ void tail_query(
    int lane, int b, int nj, int qj, int C,
    const unsigned short* __restrict__ selq,
    const float4* __restrict__ c4, const float* __restrict__ feats,
    const float* __restrict__ x, const float* __restrict__ Wo,
    const float* __restrict__ bo,
    float* __restrict__ fstage, float* __restrict__ agg,
    unsigned* __restrict__ cnt2, float* __restrict__ out)
{
    const float INF = __builtin_inff();
    const float NEGINF = -INF;
    float4 cqj = c4[nj];
    float sqnj = fmaf(cqj.x, cqj.x, fmaf(cqj.y, cqj.y, fmaf(cqj.z, cqj.z, cqj.w * cqj.w)));

    if (lane == 0) *cnt2 = 0;
    WSYNC();

    if (C <= CAP) {
        unsigned kd0 = 0xFFFFFFFFu, ki0 = 0xFFFFFFFFu; float dv0 = 0.f;
        if (lane < C) {
            unsigned idx = (unsigned)selq[lane];
            float4 cm = c4[idx];
            float s2 = fmaf(cm.x, cm.x, fmaf(cm.y, cm.y, fmaf(cm.z, cm.z, cm.w * cm.w)));
            float dt = fmaf(cqj.x, cm.x, fmaf(cqj.y, cm.y, fmaf(cqj.z, cm.z, cqj.w * cm.w)));
            float d  = fmaxf(fmaf(-2.f, dt, s2 + sqnj), 0.f);
            dv0 = d; kd0 = __float_as_uint(d); ki0 = idx;
        }
        unsigned kd1 = 0xFFFFFFFFu, ki1 = 0xFFFFFFFFu; float dv1 = 0.f;
        if (64 + lane < C) {
            unsigned idx = (unsigned)selq[64 + lane];
            float4 cm = c4[idx];
            float s2 = fmaf(cm.x, cm.x, fmaf(cm.y, cm.y, fmaf(cm.z, cm.z, cm.w * cm.w)));
            float dt = fmaf(cqj.x, cm.x, fmaf(cqj.y, cm.y, fmaf(cqj.z, cm.z, cqj.w * cm.w)));
            float d  = fmaxf(fmaf(-2.f, dt, s2 + sqnj), 0.f);
            dv1 = d; kd1 = __float_as_uint(d); ki1 = idx;
        }
        // D = exact 39th-smallest clamped d2 bits (must stay exact)
        unsigned D = 0;
        for (int bit = 30; bit >= 0; --bit) {
            unsigned t = D | (1u << bit);
            int c = (int)__popcll(__ballot(kd0 < t))
                  + (int)__popcll(__ballot(kd1 < t));
            if (c < KSEL) D = t;
        }
        int cless  = (int)__popcll(__ballot(kd0 < D))
                   + (int)__popcll(__ballot(kd1 < D));
        int tiecnt = (int)__popcll(__ballot(kd0 == D))
                   + (int)__popcll(__ballot(kd1 == D));
        int tneed = KSEL - cless;
        unsigned TI = 0xFFFFFFFFu;
        if (tiecnt > tneed) {            // rare: resolve ties by lowest index
            unsigned pi = 0;
            for (int bit = 11; bit >= 0; --bit) {
                unsigned t = pi | (1u << bit);
                int c = (int)__popcll(__ballot((kd0 == D) && (ki0 < t)))
                      + (int)__popcll(__ballot((kd1 == D) && (ki1 < t)));
                if (c < tneed) pi = t;
            }
            TI = pi;
        }
        // stage the exactly-39 selected neighbors
        bool take0 = (kd0 < D) || ((kd0 == D) && (ki0 <= TI));
        if (take0) {
            unsigned slot = atomicAdd(cnt2, 1u);
            float wgt = __expf(-10.f * dv0);
            const float4* fr = (const float4*)(feats + ((size_t)b * NN + ki0) * PPAD);
            float4 f0 = fr[0], f1 = fr[1], f2 = fr[2], f3 = fr[3], f4 = fr[4], f5 = fr[5];
            float4* row = (float4*)(fstage + slot * PPAD);
            row[0] = make_float4(f0.x * wgt, f0.y * wgt, f0.z * wgt, f0.w * wgt);
            row[1] = make_float4(f1.x * wgt, f1.y * wgt, f1.z * wgt, f1.w * wgt);
            row[2] = make_float4(f2.x * wgt, f2.y * wgt, f2.z * wgt, f2.w * wgt);
            row[3] = make_float4(f3.x * wgt, f3.y * wgt, f3.z * wgt, f3.w * wgt);
            row[4] = make_float4(f4.x * wgt, f4.y * wgt, f4.z * wgt, f4.w * wgt);
            row[5] = make_float4(f5.x * wgt, f5.y * wgt, f5.z * wgt, f5.w * wgt);
        }
        bool take1 = (kd1 < D) || ((kd1 == D) && (ki1 <= TI));
        if (take1) {
            unsigned slot = atomicAdd(cnt2, 1u);
            float wgt = __expf(-10.f * dv1);
            const float4* fr = (const float4*)(feats + ((size_t)b * NN + ki1) * PPAD);
            float4 f0 = fr[0], f1 = fr[1], f2 = fr[2], f3 = fr[3], f4 = fr[4], f5 = fr[5];
            float4* row = (float4*)(fstage + slot * PPAD);
            row[0] = make_float4(f0.x * wgt, f0.y * wgt, f0.z * wgt, f0.w * wgt);
            row[1] = make_float4(f1.x * wgt, f1.y * wgt, f1.z * wgt, f1.w * wgt);
            row[2] = make_float4(f2.x * wgt, f2.y * wgt, f2.z * wgt, f2.w * wgt);
            row[3] = make_float4(f3.x * wgt, f3.y * wgt, f3.z * wgt, f3.w * wgt);
            row[4] = make_float4(f4.x * wgt, f4.y * wgt, f4.z * wgt, f4.w * wgt);
            row[5] = make_float4(f5.x * wgt, f5.y * wgt, f5.z * wgt, f5.w * wgt);
        }
    } else {
        // degenerate fallback: exact streaming top-64 over all 4096
        float Lv = INF; int Lm = 0x7FFFFFFF;
        for (int c = 0; c < 64; ++c) {
            int m = c * 64 + lane;
            float4 cm = c4[m];
            float s2 = fmaf(cm.x, cm.x, fmaf(cm.y, cm.y, fmaf(cm.z, cm.z, cm.w * cm.w)));
            float dt = fmaf(cqj.x, cm.x, fmaf(cqj.y, cm.y, fmaf(cqj.z, cm.z, cqj.w * cm.w)));
            float v  = fmaxf(fmaf(-2.f, dt, s2 + sqnj), 0.f);
            if (m == nj) v = INF;
            sort64_pair(v, m, lane);
            if (c == 0) { Lv = v; Lm = m; }
            else        merge64(Lv, Lm, v, m, lane);
        }
        if (lane < KSEL) {
            float wgt = __expf(-10.f * Lv);
            const float4* fr = (const float4*)(feats + ((size_t)b * NN + Lm) * PPAD);
            float4 f0 = fr[0], f1 = fr[1], f2 = fr[2], f3 = fr[3], f4 = fr[4], f5 = fr[5];
            float4* row = (float4*)(fstage + lane * PPAD);
            row[0] = make_float4(f0.x * wgt, f0.y * wgt, f0.z * wgt, f0.w * wgt);
            row[1] = make_float4(f1.x * wgt, f1.y * wgt, f1.z * wgt, f1.w * wgt);
            row[2] = make_float4(f2.x * wgt, f2.y * wgt, f2.z * wgt, f2.w * wgt);
            row[3] = make_float4(f3.x * wgt, f3.y * wgt, f3.z * wgt, f3.w * wgt);
            row[4] = make_float4(f4.x * wgt, f4.y * wgt, f4.z * wgt, f4.w * wgt);
            row[5] = make_float4(f5.x * wgt, f5.y * wgt, f5.z * wgt, f5.w * wgt);
        }
    }
    WSYNC();

    // ---- max / mean over 39 neighbors: 44 lanes, split-k ----
    if (lane < 2 * PP) {
        int g  = (lane >= PP) ? 1 : 0;
        int c  = lane - g * PP;
        int k0 = g ? 20 : 0;
        int k1 = g ? KSEL : 20;
        float mx = NEGINF, sm = 0.f;
        for (int k = k0; k < k1; ++k) {
            float v = fstage[k * PPAD + c];
            mx = fmaxf(mx, v);
            sm += v;
        }
        float mx2 = __shfl(mx, lane + PP);
        float sm2 = __shfl(sm, lane + PP);
        if (lane < PP) {
            agg[c]      = fmaxf(mx, mx2);
            agg[PP + c] = (sm + sm2) * (1.f / (float)KSEL);
        }
    }
    WSYNC();

    // ---- epilogue: out = tanh([x | max | mean] @ Wo + bo), fast tanh ----
    if (lane < FOUT) {
        const float* xr = x + (size_t)qj * FIN;
        float acc = bo[lane];
        #pragma unroll
        for (int f = 0; f < FIN; ++f)
            acc = fmaf(xr[f], Wo[f * FOUT + lane], acc);
        #pragma unroll
        for (int f = 0; f < 2 * PP; ++f)
            acc = fmaf(agg[f], Wo[(FIN + f) * FOUT + lane], acc);
        float e = __expf(2.f * acc);
        float r = __builtin_amdgcn_rcpf(e + 1.f);
        out[(size_t)qj * FOUT + lane] = fmaf(-2.f, r, 1.f);
    }
    WSYNC();
}

// ---------------- main: one wave per FOUR queries, packed-fp32 scans -------------
// __launch_bounds__(128, 6): VGPR cap ~85. At (128,8) the 64-VGPR cap forced the
// packed scan's loop-carried v2f state to scratch (R13: 180+190 MB HBM traffic).
__global__ __launch_bounds__(WPB * 64, 6) void gn_main(
    const float* __restrict__ x,
    const float* __restrict__ Wo, const float* __restrict__ bo,
    const float* __restrict__ coords4, const float* __restrict__ cpair,
    const float* __restrict__ feats,
    float* __restrict__ out)
{
    __shared__ unsigned short sel_s[WPB * QW * CAP];     // candidate indices
    __shared__ float fstage_s[WPB * KSEL * PPAD];
    __shared__ float agg_s[WPB * 48];
    __shared__ unsigned cnt_s[WPB * QW];
    __shared__ unsigned cnt2_s[WPB];

    const float INF = __builtin_inff();
    const int wv    = threadIdx.x >> 6;
    const int lane  = threadIdx.x & 63;
    const int qbase = (blockIdx.x * WPB + wv) * QW;      // 4 queries, same batch
    const int b     = qbase >> 12;
    const int n0    = qbase & (NN - 1);
    unsigned short* selp = sel_s + wv * QW * CAP;
    float* fstage = fstage_s + wv * (KSEL * PPAD);
    float* agg    = agg_s + wv * 48;

    const float4* c4  = ((const float4*)coords4) + (size_t)b * NN;
    const float4* cp4 = ((const float4*)cpair) + (size_t)b * NN;   // NN float4 per batch

    // per-query constants -- individual scalars / fixed v2f splats only
    float4 cq0 = c4[n0 + 0], cq1 = c4[n0 + 1], cq2 = c4[n0 + 2], cq3 = c4[n0 + 3];
    float sq0 = fmaf(cq0.x, cq0.x, fmaf(cq0.y, cq0.y, fmaf(cq0.z, cq0.z, cq0.w * cq0.w)));
    float sq1 = fmaf(cq1.x, cq1.x, fmaf(cq1.y, cq1.y, fmaf(cq1.z, cq1.z, cq1.w * cq1.w)));
    float sq2 = fmaf(cq2.x, cq2.x, fmaf(cq2.y, cq2.y, fmaf(cq2.z, cq2.z, cq2.w * cq2.w)));
    float sq3 = fmaf(cq3.x, cq3.x, fmaf(cq3.y, cq3.y, fmaf(cq3.z, cq3.z, cq3.w * cq3.w)));

    if (lane < QW) cnt_s[wv * QW + lane] = 0;

    // ---- pass 1: packed 2-elem d2, per-query packed running min (self incl) ----
    v2f km0 = {INF, INF}, km1 = {INF, INF}, km2 = {INF, INF}, km3 = {INF, INF};
    #pragma unroll 4
    for (int i = 0; i < 32; ++i) {
        int pr = i * 64 + lane;
        float4 A  = cp4[2 * pr];         // x0,x1,y0,y1
        float4 Bv = cp4[2 * pr + 1];     // z0,z1,w0,w1
        v2f xs = {A.x,  A.y},  ys = {A.z,  A.w};
        v2f zs = {Bv.x, Bv.y}, ws = {Bv.z, Bv.w};
        v2f s2 = xs * xs;
        s2 = __builtin_elementwise_fma(ys, ys, s2);
        s2 = __builtin_elementwise_fma(zs, zs, s2);
        s2 = __builtin_elementwise_fma(ws, ws, s2);
        v2f dt0 = __builtin_elementwise_fma(xs, sp2(cq0.x), sp2(0.f));
        dt0 = __builtin_elementwise_fma(ys, sp2(cq0.y), dt0);
        dt0 = __builtin_elementwise_fma(zs, sp2(cq0.z), dt0);
        dt0 = __builtin_elementwise_fma(ws, sp2(cq0.w), dt0);
        v2f dt1 = __builtin_elementwise_fma(xs, sp2(cq1.x), sp2(0.f));
        dt1 = __builtin_elementwise_fma(ys, sp2(cq1.y), dt1);
        dt1 = __builtin_elementwise_fma(zs, sp2(cq1.z), dt1);
        dt1 = __builtin_elementwise_fma(ws, sp2(cq1.w), dt1);
        v2f dt2 = __builtin_elementwise_fma(xs, sp2(cq2.x), sp2(0.f));
        dt2 = __builtin_elementwise_fma(ys, sp2(cq2.y), dt2);
        dt2 = __builtin_elementwise_fma(zs, sp2(cq2.z), dt2);
        dt2 = __builtin_elementwise_fma(ws, sp2(cq2.w), dt2);
        v2f dt3 = __builtin_elementwise_fma(xs, sp2(cq3.x), sp2(0.f));
        dt3 = __builtin_elementwise_fma(ys, sp2(cq3.y), dt3);
        dt3 = __builtin_elementwise_fma(zs, sp2(cq3.z), dt3);
        dt3 = __builtin_elementwise_fma(ws, sp2(cq3.w), dt3);
        v2f d0 = __builtin_elementwise_fma(sp2(-2.f), dt0, s2 + sp2(sq0));
        v2f d1 = __builtin_elementwise_fma(sp2(-2.f), dt1, s2 + sp2(sq1));
        v2f d2 = __builtin_elementwise_fma(sp2(-2.f), dt2, s2 + sp2(sq2));
        v2f d3 = __builtin_elementwise_fma(sp2(-2.f), dt3, s2 + sp2(sq3));
        km0 = __builtin_elementwise_min(km0, d0);
        km1 = __builtin_elementwise_min(km1, d1);
        km2 = __builtin_elementwise_min(km2, d2);
        km3 = __builtin_elementwise_min(km3, d3);
    }
    unsigned kb0 = __float_as_uint(fmaxf(fminf(km0.x, km0.y), 0.f));
    unsigned kb1 = __float_as_uint(fmaxf(fminf(km1.x, km1.y), 0.f));
    unsigned kb2 = __float_as_uint(fmaxf(fminf(km2.x, km2.y), 0.f));
    unsigned kb3 = __float_as_uint(fmaxf(fminf(km3.x, km3.y), 0.f));

    // ---- bounds: 40th-smallest lane-min per query, TRUNCATED radix (bits 30..15)
    //      then widen low bits: UB' = p + 2^15 - 1 >= exact 40th value (superset).
    unsigned ub0 = 0, ub1 = 0, ub2 = 0, ub3 = 0;
    for (int bit = 30; bit >= 15; --bit) {
        unsigned msk = 1u << bit;
        unsigned t0 = ub0 | msk, t1 = ub1 | msk, t2 = ub2 | msk, t3 = ub3 | msk;
        if ((int)__popcll(__ballot(kb0 < t0)) < KSEL + 1) ub0 = t0;
        if ((int)__popcll(__ballot(kb1 < t1)) < KSEL + 1) ub1 = t1;
        if ((int)__popcll(__ballot(kb2 < t2)) < KSEL + 1) ub2 = t2;
        if ((int)__popcll(__ballot(kb3 < t3)) < KSEL + 1) ub3 = t3;
    }
    float UB0 = __uint_as_float(ub0 | 0x7FFFu);
    float UB1 = __uint_as_float(ub1 | 0x7FFFu);
    float UB2 = __uint_as_float(ub2 | 0x7FFFu);
    float UB3 = __uint_as_float(ub3 | 0x7FFFu);
    WSYNC();   // cnt init visible

    // ---- compact pass: packed d2 (same formula as pass 1), scalar predicates ----
    #pragma unroll 4
    for (int i = 0; i < 32; ++i) {
        int pr = i * 64 + lane;
        int m0 = 2 * pr, m1 = 2 * pr + 1;
        float4 A  = cp4[2 * pr];
        float4 Bv = cp4[2 * pr + 1];
        v2f xs = {A.x,  A.y},  ys = {A.z,  A.w};
        v2f zs = {Bv.x, Bv.y}, ws = {Bv.z, Bv.w};
        v2f s2 = xs * xs;
        s2 = __builtin_elementwise_fma(ys, ys, s2);
        s2 = __builtin_elementwise_fma(zs, zs, s2);
        s2 = __builtin_elementwise_fma(ws, ws, s2);
        v2f dt0 = __builtin_elementwise_fma(xs, sp2(cq0.x), sp2(0.f));
        dt0 = __builtin_elementwise_fma(ys, sp2(cq0.y), dt0);
        dt0 = __builtin_elementwise_fma(zs, sp2(cq0.z), dt0);
        dt0 = __builtin_elementwise_fma(ws, sp2(cq0.w), dt0);
        v2f dt1 = __builtin_elementwise_fma(xs, sp2(cq1.x), sp2(0.f));
        dt1 = __builtin_elementwise_fma(ys, sp2(cq1.y), dt1);
        dt1 = __builtin_elementwise_fma(zs, sp2(cq1.z), dt1);
        dt1 = __builtin_elementwise_fma(ws, sp2(cq1.w), dt1);
        v2f dt2 = __builtin_elementwise_fma(xs, sp2(cq2.x), sp2(0.f));
        dt2 = __builtin_elementwise_fma(ys, sp2(cq2.y), dt2);
        dt2 = __builtin_elementwise_fma(zs, sp2(cq2.z), dt2);
        dt2 = __builtin_elementwise_fma(ws, sp2(cq2.w), dt2);
        v2f dt3 = __builtin_elementwise_fma(xs, sp2(cq3.x), sp2(0.f));
        dt3 = __builtin_elementwise_fma(ys, sp2(cq3.y), dt3);
        dt3 = __builtin_elementwise_fma(zs, sp2(cq3.z), dt3);
        dt3 = __builtin_elementwise_fma(ws, sp2(cq3.w), dt3);
        v2f d0 = __builtin_elementwise_fma(sp2(-2.f), dt0, s2 + sp2(sq0));
        v2f d1 = __builtin_elementwise_fma(sp2(-2.f), dt1, s2 + sp2(sq1));
        v2f d2 = __builtin_elementwise_fma(sp2(-2.f), dt2, s2 + sp2(sq2));
        v2f d3 = __builtin_elementwise_fma(sp2(-2.f), dt3, s2 + sp2(sq3));
        if ((d0.x <= UB0) && (m0 != n0 + 0)) {
            unsigned s = atomicAdd(&cnt_s[wv * QW + 0], 1u);
            if (s < CAP) selp[0 * CAP + s] = (unsigned short)m0;
        }
        if ((d0.y <= UB0) && (m1 != n0 + 0)) {
            unsigned s = atomicAdd(&cnt_s[wv * QW + 0], 1u);
            if (s < CAP) selp[0 * CAP + s] = (unsigned short)m1;
        }
        if ((d1.x <= UB1) && (m0 != n0 + 1)) {
            unsigned s = atomicAdd(&cnt_s[wv * QW + 1], 1u);
            if (s < CAP) selp[1 * CAP + s] = (unsigned short)m0;
        }
        if ((d1.y <= UB1) && (m1 != n0 + 1)) {
            unsigned s = atomicAdd(&cnt_s[wv * QW + 1], 1u);
            if (s < CAP) selp[1 * CAP + s] = (unsigned short)m1;
        }
        if ((d2.x <= UB2) && (m0 != n0 + 2)) {
            unsigned s = atomicAdd(&cnt_s[wv * QW + 2], 1u);
            if (s < CAP) selp[2 * CAP + s] = (unsigned short)m0;
        }
        if ((d2.y <= UB2) && (m1 != n0 + 2)) {
            unsigned s = atomicAdd(&cnt_s[wv * QW + 2], 1u);
            if (s < CAP) selp[2 * CAP + s] = (unsigned short)m1;
        }
        if ((d3.x <= UB3) && (m0 != n0 + 3)) {
            unsigned s = atomicAdd(&cnt_s[wv * QW + 3], 1u);
            if (s < CAP) selp[3 * CAP + s] = (unsigned short)m0;
        }
        if ((d3.y <= UB3) && (m1 != n0 + 3)) {
            unsigned s = atomicAdd(&cnt_s[wv * QW + 3], 1u);
            if (s < CAP) selp[3 * CAP + s] = (unsigned short)m1;
        }
    }
    WSYNC();

    // ---- four explicit tail calls (no runtime-indexed private state) ----
    tail_query(lane, b, n0 + 0, qbase + 0, (int)cnt_s[wv * QW + 0], selp + 0 * CAP,
               c4, feats, x, Wo, bo, fstage, agg, &cnt2_s[wv], out);
    tail_query(lane, b, n0 + 1, qbase + 1, (int)cnt_s[wv * QW + 1], selp + 1 * CAP,
               c4, feats, x, Wo, bo, fstage, agg, &cnt2_s[wv], out);
    tail_query(lane, b, n0 + 2, qbase + 2, (int)cnt_s[wv * QW + 2], selp + 2 * CAP,
               c4, feats, x, Wo, bo, fstage, agg, &cnt2_s[wv], out);
    tail_query(lane, b, n0 + 3, qbase + 3, (int)cnt_s[wv * QW + 3], selp + 3 * CAP,
               c4, feats, x, Wo, bo, fstage, agg, &cnt2_s[wv], out);
}

extern "C" void kernel_launch(void* const* d_in, const int* in_sizes, int n_in,
                              void* d_out, int out_size, void* d_ws, size_t ws_size,
                              hipStream_t stream) {
    const float* x  = (const float*)d_in[0];
    const float* Wf = (const float*)d_in[1];
    const float* bf = (const float*)d_in[2];
    const float* Ws = (const float*)d_in[3];
    const float* bs = (const float*)d_in[4];
    const float* Wo = (const float*)d_in[5];
    const float* bo = (const float*)d_in[6];
    float* outp = (float*)d_out;

    float* ws      = (float*)d_ws;
    float* coords4 = ws;                      // 32768*4  = 131072 floats
    float* cpair   = ws + 131072;             // 32768*4  = 131072 floats (pair-SoA)
    float* feats   = ws + 262144;             // 32768*24 = 786432 floats

    gn_pre<<<32768 / 256, 256, 0, stream>>>(x, Wf, bf, Ws, bs, coords4, cpair, feats);
    gn_main<<<32768 / (WPB * QW), WPB * 64, 0, stream>>>(x, Wo, bo, coords4, cpair, feats, outp);
}

// Round 15
// 232.982 us; speedup vs baseline: 1.5089x; 1.0259x over previous
//
#include <hip/hip_runtime.h>
#include <cmath>

#define NN    4096
#define FIN   32
#define KSEL  39      // neighbors kept (top-40 minus self)
#define PP    22
#define PPAD  24
#define FOUT  48
#define WPB   2       // waves per block
#define QW    4       // queries per wave
#define CAP   128     // candidate cap per query (fallback if exceeded)

#define WSYNC() asm volatile("s_waitcnt lgkmcnt(0)" ::: "memory")

// order-preserving float->uint (total order, handles negatives)
__device__ __forceinline__ unsigned keyof(float f) {
    unsigned u = __float_as_uint(f);
    return ((int)u < 0) ? ~u : (u | 0x80000000u);
}
__device__ __forceinline__ float keyinv(unsigned k) {
    return ((int)k < 0) ? __uint_as_float(k & 0x7FFFFFFFu) : __uint_as_float(~k);
}

// ---------------- precompute: one thread per point -------------------------------
// feats (padded 24), coords float4, h = |coords|^2 / 2.
__global__ __launch_bounds__(256) void gn_pre(
    const float* __restrict__ x,
    const float* __restrict__ Wf, const float* __restrict__ bf,
    const float* __restrict__ Ws, const float* __restrict__ bs,
    float* __restrict__ coords4, float* __restrict__ harr, float* __restrict__ feats)
{
    int p = blockIdx.x * 256 + threadIdx.x;

    const float4* xr4 = (const float4*)(x + (size_t)p * FIN);
    float xv[FIN];
    #pragma unroll
    for (int i = 0; i < 8; ++i) {
        float4 t = xr4[i];
        xv[4*i] = t.x; xv[4*i+1] = t.y; xv[4*i+2] = t.z; xv[4*i+3] = t.w;
    }

    float fa[PP];
    #pragma unroll
    for (int c = 0; c < PP; ++c) fa[c] = bf[c];
    #pragma unroll
    for (int i = 0; i < FIN; ++i) {
        float xi = xv[i];
        #pragma unroll
        for (int c = 0; c < PP; ++c) fa[c] = fmaf(xi, Wf[i * PP + c], fa[c]);
    }

    float ca[4];
    #pragma unroll
    for (int c = 0; c < 4; ++c) ca[c] = bs[c];
    #pragma unroll
    for (int i = 0; i < FIN; ++i) {
        float xi = xv[i];
        #pragma unroll
        for (int c = 0; c < 4; ++c) ca[c] = fmaf(xi, Ws[i * 4 + c], ca[c]);
    }

    float4* fw = (float4*)(feats + (size_t)p * PPAD);
    fw[0] = make_float4(fa[0],  fa[1],  fa[2],  fa[3]);
    fw[1] = make_float4(fa[4],  fa[5],  fa[6],  fa[7]);
    fw[2] = make_float4(fa[8],  fa[9],  fa[10], fa[11]);
    fw[3] = make_float4(fa[12], fa[13], fa[14], fa[15]);
    fw[4] = make_float4(fa[16], fa[17], fa[18], fa[19]);
    fw[5] = make_float4(fa[20], fa[21], 0.f, 0.f);

    ((float4*)coords4)[p] = make_float4(ca[0], ca[1], ca[2], ca[3]);
    harr[p] = 0.5f * fmaf(ca[0], ca[0], fmaf(ca[1], ca[1], fmaf(ca[2], ca[2], ca[3] * ca[3])));
}

// ---- fallback-only helpers (degenerate C > CAP path) ----------------------------
__device__ __forceinline__ void sort64_pair(float& v, int& m, int lane) {
    #pragma unroll
    for (int k = 2; k <= 64; k <<= 1) {
        #pragma unroll
        for (int j = k >> 1; j >= 1; j >>= 1) {
            float ov = __shfl_xor(v, j);
            int   om = __shfl_xor(m, j);
            bool keepMin = (((lane & j) == 0) == ((lane & k) == 0));
            bool less = (ov < v) || (ov == v && om < m);
            bool take = (less == keepMin);
            v = take ? ov : v;
            m = take ? om : m;
        }
    }
}
__device__ __forceinline__ void merge64(float& Lv, int& Lm, float cv, int cm, int lane) {
    float rv = __shfl_xor(cv, 63);
    int   rm = __shfl_xor(cm, 63);
    bool less = (rv < Lv) || (rv == Lv && rm < Lm);
    if (less) { Lv = rv; Lm = rm; }
    #pragma unroll
    for (int j = 32; j >= 1; j >>= 1) {
        float ov = __shfl_xor(Lv, j);
        int   om = __shfl_xor(Lm, j);
        bool lower = ((lane & j) == 0);
        bool l2 = (ov < Lv) || (ov == Lv && om < Lm);
        bool take = (l2 == lower);
        Lv = take ? ov : Lv;
        Lm = take ? om : Lm;
    }
}

// ---------------- per-query tail: selection + stage + aggregate + epilogue -------
// ALL state scalar; candidates' f values come from LDS (no coord reloads).
__device__ __forceinline__ void tail_query(
    int lane, int b, int nj, int qj, int C, float sqnj,
    const unsigned short* __restrict__ selq, const float* __restrict__ fselq,
    const float4* __restrict__ c4, const float* __restrict__ feats,
    const float* __restrict__ x, const float* __restrict__ Wo,
    const float* __restrict__ bo,
    float* __restrict__ fstage, float* __restrict__ agg,
    unsigned* __restrict__ cnt2, float* __restrict__ out)
{
    const float INF = __builtin_inff();
    const float NEGINF = -INF;

    if (lane == 0) *cnt2 = 0;
    WSYNC();

    if (C <= CAP) {
        unsigned kd0 = 0xFFFFFFFFu, ki0 = 0xFFFFFFFFu; float fv0 = 0.f;
        if (lane < C) {
            ki0 = (unsigned)selq[lane];
            fv0 = fselq[lane];
            kd0 = keyof(fv0);
        }
        unsigned kd1 = 0xFFFFFFFFu, ki1 = 0xFFFFFFFFu; float fv1 = 0.f;
        if (64 + lane < C) {
            ki1 = (unsigned)selq[64 + lane];
            fv1 = fselq[64 + lane];
            kd1 = keyof(fv1);
        }
        // D = exact 39th-smallest f-key (full 32-bit radix; keys span full range)
        unsigned D = 0;
        for (int bit = 31; bit >= 0; --bit) {
            unsigned t = D | (1u << bit);
            int c = (int)__popcll(__ballot(kd0 < t))
                  + (int)__popcll(__ballot(kd1 < t));
            if (c < KSEL) D = t;
        }
        int cless  = (int)__popcll(__ballot(kd0 < D))
                   + (int)__popcll(__ballot(kd1 < D));
        int tiecnt = (int)__popcll(__ballot(kd0 == D))
                   + (int)__popcll(__ballot(kd1 == D));
        int tneed = KSEL - cless;
        unsigned TI = 0xFFFFFFFFu;
        if (tiecnt > tneed) {            // rare: resolve ties by lowest index
            unsigned pi = 0;
            for (int bit = 11; bit >= 0; --bit) {
                unsigned t = pi | (1u << bit);
                int c = (int)__popcll(__ballot((kd0 == D) && (ki0 < t)))
                      + (int)__popcll(__ballot((kd1 == D) && (ki1 < t)));
                if (c < tneed) pi = t;
            }
            TI = pi;
        }
        // stage the exactly-39 selected neighbors; d2 = max(2f + sq, 0)
        bool take0 = (kd0 < D) || ((kd0 == D) && (ki0 <= TI));
        if (take0) {
            unsigned slot = atomicAdd(cnt2, 1u);
            float d2  = fmaxf(fmaf(2.f, fv0, sqnj), 0.f);
            float wgt = __expf(-10.f * d2);
            const float4* fr = (const float4*)(feats + ((size_t)b * NN + ki0) * PPAD);
            float4 f0 = fr[0], f1 = fr[1], f2 = fr[2], f3 = fr[3], f4 = fr[4], f5 = fr[5];
            float4* row = (float4*)(fstage + slot * PPAD);
            row[0] = make_float4(f0.x * wgt, f0.y * wgt, f0.z * wgt, f0.w * wgt);
            row[1] = make_float4(f1.x * wgt, f1.y * wgt, f1.z * wgt, f1.w * wgt);
            row[2] = make_float4(f2.x * wgt, f2.y * wgt, f2.z * wgt, f2.w * wgt);
            row[3] = make_float4(f3.x * wgt, f3.y * wgt, f3.z * wgt, f3.w * wgt);
            row[4] = make_float4(f4.x * wgt, f4.y * wgt, f4.z * wgt, f4.w * wgt);
            row[5] = make_float4(f5.x * wgt, f5.y * wgt, f5.z * wgt, f5.w * wgt);
        }
        bool take1 = (kd1 < D) || ((kd1 == D) && (ki1 <= TI));
        if (take1) {
            unsigned slot = atomicAdd(cnt2, 1u);
            float d2  = fmaxf(fmaf(2.f, fv1, sqnj), 0.f);
            float wgt = __expf(-10.f * d2);
            const float4* fr = (const float4*)(feats + ((size_t)b * NN + ki1) * PPAD);
            float4 f0 = fr[0], f1 = fr[1], f2 = fr[2], f3 = fr[3], f4 = fr[4], f5 = fr[5];
            float4* row = (float4*)(fstage + slot * PPAD);
            row[0] = make_float4(f0.x * wgt, f0.y * wgt, f0.z * wgt, f0.w * wgt);
            row[1] = make_float4(f1.x * wgt, f1.y * wgt, f1.z * wgt, f1.w * wgt);
            row[2] = make_float4(f2.x * wgt, f2.y * wgt, f2.z * wgt, f2.w * wgt);
            row[3] = make_float4(f3.x * wgt, f3.y * wgt, f3.z * wgt, f3.w * wgt);
            row[4] = make_float4(f4.x * wgt, f4.y * wgt, f4.z * wgt, f4.w * wgt);
            row[5] = make_float4(f5.x * wgt, f5.y * wgt, f5.z * wgt, f5.w * wgt);
        }
    } else {
        // degenerate fallback: exact streaming top-64 over all 4096 (d2-ranked)
        float4 cqj = c4[nj];
        float Lv = INF; int Lm = 0x7FFFFFFF;
        for (int c = 0; c < 64; ++c) {
            int m = c * 64 + lane;
            float4 cm = c4[m];
            float s2 = fmaf(cm.x, cm.x, fmaf(cm.y, cm.y, fmaf(cm.z, cm.z, cm.w * cm.w)));
            float dt = fmaf(cqj.x, cm.x, fmaf(cqj.y, cm.y, fmaf(cqj.z, cm.z, cqj.w * cm.w)));
            float v  = fmaxf(fmaf(-2.f, dt, s2 + sqnj), 0.f);
            if (m == nj) v = INF;
            sort64_pair(v, m, lane);
            if (c == 0) { Lv = v; Lm = m; }
            else        merge64(Lv, Lm, v, m, lane);
        }
        if (lane < KSEL) {
            float wgt = __expf(-10.f * Lv);
            const float4* fr = (const float4*)(feats + ((size_t)b * NN + Lm) * PPAD);
            float4 f0 = fr[0], f1 = fr[1], f2 = fr[2], f3 = fr[3], f4 = fr[4], f5 = fr[5];
            float4* row = (float4*)(fstage + lane * PPAD);
            row[0] = make_float4(f0.x * wgt, f0.y * wgt, f0.z * wgt, f0.w * wgt);
            row[1] = make_float4(f1.x * wgt, f1.y * wgt, f1.z * wgt, f1.w * wgt);
            row[2] = make_float4(f2.x * wgt, f2.y * wgt, f2.z * wgt, f2.w * wgt);
            row[3] = make_float4(f3.x * wgt, f3.y * wgt, f3.z * wgt, f3.w * wgt);
            row[4] = make_float4(f4.x * wgt, f4.y * wgt, f4.z * wgt, f4.w * wgt);
            row[5] = make_float4(f5.x * wgt, f5.y * wgt, f5.z * wgt, f5.w * wgt);
        }
    }
    WSYNC();

    // ---- max / mean over 39 neighbors: 44 lanes, split-k ----
    if (lane < 2 * PP) {
        int g  = (lane >= PP) ? 1 : 0;
        int c  = lane - g * PP;
        int k0 = g ? 20 : 0;
        int k1 = g ? KSEL : 20;
        float mx = NEGINF, sm = 0.f;
        for (int k = k0; k < k1; ++k) {
            float v = fstage[k * PPAD + c];
            mx = fmaxf(mx, v);
            sm += v;
        }
        float mx2 = __shfl(mx, lane + PP);
        float sm2 = __shfl(sm, lane + PP);
        if (lane < PP) {
            agg[c]      = fmaxf(mx, mx2);
            agg[PP + c] = (sm + sm2) * (1.f / (float)KSEL);
        }
    }
    WSYNC();

    // ---- epilogue: out = tanh([x | max | mean] @ Wo + bo), fast tanh ----
    if (lane < FOUT) {
        const float* xr = x + (size_t)qj * FIN;
        float acc = bo[lane];
        #pragma unroll
        for (int f = 0; f < FIN; ++f)
            acc = fmaf(xr[f], Wo[f * FOUT + lane], acc);
        #pragma unroll
        for (int f = 0; f < 2 * PP; ++f)
            acc = fmaf(agg[f], Wo[(FIN + f) * FOUT + lane], acc);
        float e = __expf(2.f * acc);
        float r = __builtin_amdgcn_rcpf(e + 1.f);
        out[(size_t)qj * FOUT + lane] = fmaf(-2.f, r, 1.f);
    }
    WSYNC();
}

// ---------------- main: one wave per FOUR queries, f = h - q.m scans -------------
__global__ __launch_bounds__(WPB * 64, 8) void gn_main(
    const float* __restrict__ x,
    const float* __restrict__ Wo, const float* __restrict__ bo,
    const float* __restrict__ coords4, const float* __restrict__ harr,
    const float* __restrict__ feats,
    float* __restrict__ out)
{
    __shared__ unsigned short sel_s[WPB * QW * CAP];     // candidate indices
    __shared__ float fsel_s[WPB * QW * CAP];             // candidate f values
    __shared__ float fstage_s[WPB * KSEL * PPAD];
    __shared__ float agg_s[WPB * 48];
    __shared__ unsigned cnt_s[WPB * QW];
    __shared__ unsigned cnt2_s[WPB];

    const float INF = __builtin_inff();
    const int wv    = threadIdx.x >> 6;
    const int lane  = threadIdx.x & 63;
    const int qbase = (blockIdx.x * WPB + wv) * QW;      // 4 queries, same batch
    const int b     = qbase >> 12;
    const int n0    = qbase & (NN - 1);
    unsigned short* selp  = sel_s  + wv * QW * CAP;
    float*          fselp = fsel_s + wv * QW * CAP;
    float* fstage = fstage_s + wv * (KSEL * PPAD);
    float* agg    = agg_s + wv * 48;

    const float4* c4 = ((const float4*)coords4) + (size_t)b * NN;
    const float*  hB = harr + (size_t)b * NN;

    // per-query constants -- individual scalars only
    float4 cq0 = c4[n0 + 0], cq1 = c4[n0 + 1], cq2 = c4[n0 + 2], cq3 = c4[n0 + 3];
    float sq0 = fmaf(cq0.x, cq0.x, fmaf(cq0.y, cq0.y, fmaf(cq0.z, cq0.z, cq0.w * cq0.w)));
    float sq1 = fmaf(cq1.x, cq1.x, fmaf(cq1.y, cq1.y, fmaf(cq1.z, cq1.z, cq1.w * cq1.w)));
    float sq2 = fmaf(cq2.x, cq2.x, fmaf(cq2.y, cq2.y, fmaf(cq2.z, cq2.z, cq2.w * cq2.w)));
    float sq3 = fmaf(cq3.x, cq3.x, fmaf(cq3.y, cq3.y, fmaf(cq3.z, cq3.z, cq3.w * cq3.w)));

    if (lane < QW) cnt_s[wv * QW + lane] = 0;

    // ---- pass 1: f = h - q.m per query, running min (self included) ----
    float km0 = INF, km1 = INF, km2 = INF, km3 = INF;
    #pragma unroll 4
    for (int i = 0; i < 64; ++i) {
        int m = i * 64 + lane;
        float4 cm = c4[m];
        float hm = hB[m];
        float f0 = fmaf(-cq0.x, cm.x, hm);
        f0 = fmaf(-cq0.y, cm.y, f0);
        f0 = fmaf(-cq0.z, cm.z, f0);
        f0 = fmaf(-cq0.w, cm.w, f0);
        float f1 = fmaf(-cq1.x, cm.x, hm);
        f1 = fmaf(-cq1.y, cm.y, f1);
        f1 = fmaf(-cq1.z, cm.z, f1);
        f1 = fmaf(-cq1.w, cm.w, f1);
        float f2 = fmaf(-cq2.x, cm.x, hm);
        f2 = fmaf(-cq2.y, cm.y, f2);
        f2 = fmaf(-cq2.z, cm.z, f2);
        f2 = fmaf(-cq2.w, cm.w, f2);
        float f3 = fmaf(-cq3.x, cm.x, hm);
        f3 = fmaf(-cq3.y, cm.y, f3);
        f3 = fmaf(-cq3.z, cm.z, f3);
        f3 = fmaf(-cq3.w, cm.w, f3);
        km0 = fminf(km0, f0);
        km1 = fminf(km1, f1);
        km2 = fminf(km2, f2);
        km3 = fminf(km3, f3);
    }
    unsigned kb0 = keyof(km0);
    unsigned kb1 = keyof(km1);
    unsigned kb2 = keyof(km2);
    unsigned kb3 = keyof(km3);

    // ---- bounds: 40th-smallest lane-min f-key, TRUNCATED radix (bits 31..15),
    //      widen low bits -> exact superset threshold in f-space.
    unsigned ub0 = 0, ub1 = 0, ub2 = 0, ub3 = 0;
    for (int bit = 31; bit >= 15; --bit) {
        unsigned msk = 1u << bit;
        unsigned t0 = ub0 | msk, t1 = ub1 | msk, t2 = ub2 | msk, t3 = ub3 | msk;
        if ((int)__popcll(__ballot(kb0 < t0)) < KSEL + 1) ub0 = t0;
        if ((int)__popcll(__ballot(kb1 < t1)) < KSEL + 1) ub1 = t1;
        if ((int)__popcll(__ballot(kb2 < t2)) < KSEL + 1) ub2 = t2;
        if ((int)__popcll(__ballot(kb3 < t3)) < KSEL + 1) ub3 = t3;
    }
    float UB0 = keyinv(ub0 | 0x7FFFu);
    float UB1 = keyinv(ub1 | 0x7FFFu);
    float UB2 = keyinv(ub2 | 0x7FFFu);
    float UB3 = keyinv(ub3 | 0x7FFFu);
    WSYNC();   // cnt init visible

    // ---- compact pass: f <= UB, store (idx, f) to LDS ----
    #pragma unroll 4
    for (int i = 0; i < 64; ++i) {
        int m = i * 64 + lane;
        float4 cm = c4[m];
        float hm = hB[m];
        float f0 = fmaf(-cq0.x, cm.x, hm);
        f0 = fmaf(-cq0.y, cm.y, f0);
        f0 = fmaf(-cq0.z, cm.z, f0);
        f0 = fmaf(-cq0.w, cm.w, f0);
        float f1 = fmaf(-cq1.x, cm.x, hm);
        f1 = fmaf(-cq1.y, cm.y, f1);
        f1 = fmaf(-cq1.z, cm.z, f1);
        f1 = fmaf(-cq1.w, cm.w, f1);
        float f2 = fmaf(-cq2.x, cm.x, hm);
        f2 = fmaf(-cq2.y, cm.y, f2);
        f2 = fmaf(-cq2.z, cm.z, f2);
        f2 = fmaf(-cq2.w, cm.w, f2);
        float f3 = fmaf(-cq3.x, cm.x, hm);
        f3 = fmaf(-cq3.y, cm.y, f3);
        f3 = fmaf(-cq3.z, cm.z, f3);
        f3 = fmaf(-cq3.w, cm.w, f3);
        if ((f0 <= UB0) && (m != n0 + 0)) {
            unsigned s = atomicAdd(&cnt_s[wv * QW + 0], 1u);
            if (s < CAP) { selp[0 * CAP + s] = (unsigned short)m; fselp[0 * CAP + s] = f0; }
        }
        if ((f1 <= UB1) && (m != n0 + 1)) {
            unsigned s = atomicAdd(&cnt_s[wv * QW + 1], 1u);
            if (s < CAP) { selp[1 * CAP + s] = (unsigned short)m; fselp[1 * CAP + s] = f1; }
        }
        if ((f2 <= UB2) && (m != n0 + 2)) {
            unsigned s = atomicAdd(&cnt_s[wv * QW + 2], 1u);
            if (s < CAP) { selp[2 * CAP + s] = (unsigned short)m; fselp[2 * CAP + s] = f2; }
        }
        if ((f3 <= UB3) && (m != n0 + 3)) {
            unsigned s = atomicAdd(&cnt_s[wv * QW + 3], 1u);
            if (s < CAP) { selp[3 * CAP + s] = (unsigned short)m; fselp[3 * CAP + s] = f3; }
        }
    }
    WSYNC();

    // ---- four explicit tail calls (no runtime-indexed private state) ----
    tail_query(lane, b, n0 + 0, qbase + 0, (int)cnt_s[wv * QW + 0], sq0,
               selp + 0 * CAP, fselp + 0 * CAP,
               c4, feats, x, Wo, bo, fstage, agg, &cnt2_s[wv], out);
    tail_query(lane, b, n0 + 1, qbase + 1, (int)cnt_s[wv * QW + 1], sq1,
               selp + 1 * CAP, fselp + 1 * CAP,
               c4, feats, x, Wo, bo, fstage, agg, &cnt2_s[wv], out);
    tail_query(lane, b, n0 + 2, qbase + 2, (int)cnt_s[wv * QW + 2], sq2,
               selp + 2 * CAP, fselp + 2 * CAP,
               c4, feats, x, Wo, bo, fstage, agg, &cnt2_s[wv], out);
    tail_query(lane, b, n0 + 3, qbase + 3, (int)cnt_s[wv * QW + 3], sq3,
               selp + 3 * CAP, fselp + 3 * CAP,
               c4, feats, x, Wo, bo, fstage, agg, &cnt2_s[wv], out);
}

extern "C" void kernel_launch(void* const* d_in, const int* in_sizes, int n_in,
                              void* d_out, int out_size, void* d_ws, size_t ws_size,
                              hipStream_t stream) {
    const float* x  = (const float*)d_in[0];
    const float* Wf = (const float*)d_in[1];
    const float* bf = (const float*)d_in[2];
    const float* Ws = (const float*)d_in[3];
    const float* bs = (const float*)d_in[4];
    const float* Wo = (const float*)d_in[5];
    const float* bo = (const float*)d_in[6];
    float* outp = (float*)d_out;

    float* ws      = (float*)d_ws;
    float* coords4 = ws;                      // 32768*4  = 131072 floats
    float* harr    = ws + 131072;             // 32768 floats
    float* feats   = ws + 131072 + 32768;     // 32768*24 = 786432 floats

    gn_pre<<<32768 / 256, 256, 0, stream>>>(x, Wf, bf, Ws, bs, coords4, harr, feats);
    gn_main<<<32768 / (WPB * QW), WPB * 64, 0, stream>>>(x, Wo, bo, coords4, harr, feats, outp);
}

// Round 16
// 201.391 us; speedup vs baseline: 1.7455x; 1.1569x over previous
//
#include <hip/hip_runtime.h>
#include <cmath>

#define NN    4096
#define FIN   32
#define KSEL  39      // neighbors kept (top-40 minus self)
#define PP    22
#define PPAD  24
#define FOUT  48
#define WPB   2       // waves per block
#define QW    4       // queries per wave
#define CAP   128     // candidate cap per query (fallback if exceeded)

#define WSYNC() asm volatile("s_waitcnt lgkmcnt(0)" ::: "memory")

// order-preserving float->uint (total order, handles negatives)
__device__ __forceinline__ unsigned keyof(float f) {
    unsigned u = __float_as_uint(f);
    return ((int)u < 0) ? ~u : (u | 0x80000000u);
}
__device__ __forceinline__ float keyinv(unsigned k) {
    return ((int)k < 0) ? __uint_as_float(k & 0x7FFFFFFFu) : __uint_as_float(~k);
}

// ---------------- precompute: one thread per point -------------------------------
// feats (padded 24), coords float4, h = |coords|^2 / 2.
__global__ __launch_bounds__(256) void gn_pre(
    const float* __restrict__ x,
    const float* __restrict__ Wf, const float* __restrict__ bf,
    const float* __restrict__ Ws, const float* __restrict__ bs,
    float* __restrict__ coords4, float* __restrict__ harr, float* __restrict__ feats)
{
    int p = blockIdx.x * 256 + threadIdx.x;

    const float4* xr4 = (const float4*)(x + (size_t)p * FIN);
    float xv[FIN];
    #pragma unroll
    for (int i = 0; i < 8; ++i) {
        float4 t = xr4[i];
        xv[4*i] = t.x; xv[4*i+1] = t.y; xv[4*i+2] = t.z; xv[4*i+3] = t.w;
    }

    float fa[PP];
    #pragma unroll
    for (int c = 0; c < PP; ++c) fa[c] = bf[c];
    #pragma unroll
    for (int i = 0; i < FIN; ++i) {
        float xi = xv[i];
        #pragma unroll
        for (int c = 0; c < PP; ++c) fa[c] = fmaf(xi, Wf[i * PP + c], fa[c]);
    }

    float ca[4];
    #pragma unroll
    for (int c = 0; c < 4; ++c) ca[c] = bs[c];
    #pragma unroll
    for (int i = 0; i < FIN; ++i) {
        float xi = xv[i];
        #pragma unroll
        for (int c = 0; c < 4; ++c) ca[c] = fmaf(xi, Ws[i * 4 + c], ca[c]);
    }

    float4* fw = (float4*)(feats + (size_t)p * PPAD);
    fw[0] = make_float4(fa[0],  fa[1],  fa[2],  fa[3]);
    fw[1] = make_float4(fa[4],  fa[5],  fa[6],  fa[7]);
    fw[2] = make_float4(fa[8],  fa[9],  fa[10], fa[11]);
    fw[3] = make_float4(fa[12], fa[13], fa[14], fa[15]);
    fw[4] = make_float4(fa[16], fa[17], fa[18], fa[19]);
    fw[5] = make_float4(fa[20], fa[21], 0.f, 0.f);

    ((float4*)coords4)[p] = make_float4(ca[0], ca[1], ca[2], ca[3]);
    harr[p] = 0.5f * fmaf(ca[0], ca[0], fmaf(ca[1], ca[1], fmaf(ca[2], ca[2], ca[3] * ca[3])));
}

// ---- fallback-only helpers (degenerate C > CAP path) ----------------------------
__device__ __forceinline__ void sort64_pair(float& v, int& m, int lane) {
    #pragma unroll
    for (int k = 2; k <= 64; k <<= 1) {
        #pragma unroll
        for (int j = k >> 1; j >= 1; j >>= 1) {
            float ov = __shfl_xor(v, j);
            int   om = __shfl_xor(m, j);
            bool keepMin = (((lane & j) == 0) == ((lane & k) == 0));
            bool less = (ov < v) || (ov == v && om < m);
            bool take = (less == keepMin);
            v = take ? ov : v;
            m = take ? om : m;
        }
    }
}
__device__ __forceinline__ void merge64(float& Lv, int& Lm, float cv, int cm, int lane) {
    float rv = __shfl_xor(cv, 63);
    int   rm = __shfl_xor(cm, 63);
    bool less = (rv < Lv) || (rv == Lv && rm < Lm);
    if (less) { Lv = rv; Lm = rm; }
    #pragma unroll
    for (int j = 32; j >= 1; j >>= 1) {
        float ov = __shfl_xor(Lv, j);
        int   om = __shfl_xor(Lm, j);
        bool lower = ((lane & j) == 0);
        bool l2 = (ov < Lv) || (ov == Lv && om < Lm);
        bool take = (l2 == lower);
        Lv = take ? ov : Lv;
        Lm = take ? om : Lm;
    }
}

// ---------------- per-query tail (R12-identical): selection + stage + agg + epi --
// ALL state scalar. Recomputes candidate d2 from c4 (cheap, L1-hot; keeps VGPR low).
__device__ __forceinline__ void tail_query(
    int lane, int b, int nj, int qj, int C,
    const unsigned short* __restrict__ selq,
    const float4* __restrict__ c4, const float* __restrict__ feats,
    const float* __restrict__ x, const float* __restrict__ Wo,
    const float* __restrict__ bo,
    float* __restrict__ fstage, float* __restrict__ agg,
    unsigned* __restrict__ cnt2, float* __restrict__ out)
{
    const float INF = __builtin_inff();
    const float NEGINF = -INF;
    float4 cqj = c4[nj];
    float sqnj = fmaf(cqj.x, cqj.x, fmaf(cqj.y, cqj.y, fmaf(cqj.z, cqj.z, cqj.w * cqj.w)));

    if (lane == 0) *cnt2 = 0;
    WSYNC();

    if (C <= CAP) {
        unsigned kd0 = 0xFFFFFFFFu, ki0 = 0xFFFFFFFFu; float dv0 = 0.f;
        if (lane < C) {
            unsigned idx = (unsigned)selq[lane];
            float4 cm = c4[idx];
            float s2 = fmaf(cm.x, cm.x, fmaf(cm.y, cm.y, fmaf(cm.z, cm.z, cm.w * cm.w)));
            float dt = fmaf(cqj.x, cm.x, fmaf(cqj.y, cm.y, fmaf(cqj.z, cm.z, cqj.w * cm.w)));
            float d  = fmaxf(fmaf(-2.f, dt, s2 + sqnj), 0.f);
            dv0 = d; kd0 = __float_as_uint(d); ki0 = idx;
        }
        unsigned kd1 = 0xFFFFFFFFu, ki1 = 0xFFFFFFFFu; float dv1 = 0.f;
        if (64 + lane < C) {
            unsigned idx = (unsigned)selq[64 + lane];
            float4 cm = c4[idx];
            float s2 = fmaf(cm.x, cm.x, fmaf(cm.y, cm.y, fmaf(cm.z, cm.z, cm.w * cm.w)));
            float dt = fmaf(cqj.x, cm.x, fmaf(cqj.y, cm.y, fmaf(cqj.z, cm.z, cqj.w * cm.w)));
            float d  = fmaxf(fmaf(-2.f, dt, s2 + sqnj), 0.f);
            dv1 = d; kd1 = __float_as_uint(d); ki1 = idx;
        }
        // D = exact 39th-smallest clamped d2 bits (plain IEEE bits, d >= 0)
        unsigned D = 0;
        for (int bit = 30; bit >= 0; --bit) {
            unsigned t = D | (1u << bit);
            int c = (int)__popcll(__ballot(kd0 < t))
                  + (int)__popcll(__ballot(kd1 < t));
            if (c < KSEL) D = t;
        }
        int cless  = (int)__popcll(__ballot(kd0 < D))
                   + (int)__popcll(__ballot(kd1 < D));
        int tiecnt = (int)__popcll(__ballot(kd0 == D))
                   + (int)__popcll(__ballot(kd1 == D));
        int tneed = KSEL - cless;
        unsigned TI = 0xFFFFFFFFu;
        if (tiecnt > tneed) {            // rare: resolve ties by lowest index
            unsigned pi = 0;
            for (int bit = 11; bit >= 0; --bit) {
                unsigned t = pi | (1u << bit);
                int c = (int)__popcll(__ballot((kd0 == D) && (ki0 < t)))
                      + (int)__popcll(__ballot((kd1 == D) && (ki1 < t)));
                if (c < tneed) pi = t;
            }
            TI = pi;
        }
        // stage the exactly-39 selected neighbors
        bool take0 = (kd0 < D) || ((kd0 == D) && (ki0 <= TI));
        if (take0) {
            unsigned slot = atomicAdd(cnt2, 1u);
            float wgt = __expf(-10.f * dv0);
            const float4* fr = (const float4*)(feats + ((size_t)b * NN + ki0) * PPAD);
            float4 f0 = fr[0], f1 = fr[1], f2 = fr[2], f3 = fr[3], f4 = fr[4], f5 = fr[5];
            float4* row = (float4*)(fstage + slot * PPAD);
            row[0] = make_float4(f0.x * wgt, f0.y * wgt, f0.z * wgt, f0.w * wgt);
            row[1] = make_float4(f1.x * wgt, f1.y * wgt, f1.z * wgt, f1.w * wgt);
            row[2] = make_float4(f2.x * wgt, f2.y * wgt, f2.z * wgt, f2.w * wgt);
            row[3] = make_float4(f3.x * wgt, f3.y * wgt, f3.z * wgt, f3.w * wgt);
            row[4] = make_float4(f4.x * wgt, f4.y * wgt, f4.z * wgt, f4.w * wgt);
            row[5] = make_float4(f5.x * wgt, f5.y * wgt, f5.z * wgt, f5.w * wgt);
        }
        bool take1 = (kd1 < D) || ((kd1 == D) && (ki1 <= TI));
        if (take1) {
            unsigned slot = atomicAdd(cnt2, 1u);
            float wgt = __expf(-10.f * dv1);
            const float4* fr = (const float4*)(feats + ((size_t)b * NN + ki1) * PPAD);
            float4 f0 = fr[0], f1 = fr[1], f2 = fr[2], f3 = fr[3], f4 = fr[4], f5 = fr[5];
            float4* row = (float4*)(fstage + slot * PPAD);
            row[0] = make_float4(f0.x * wgt, f0.y * wgt, f0.z * wgt, f0.w * wgt);
            row[1] = make_float4(f1.x * wgt, f1.y * wgt, f1.z * wgt, f1.w * wgt);
            row[2] = make_float4(f2.x * wgt, f2.y * wgt, f2.z * wgt, f2.w * wgt);
            row[3] = make_float4(f3.x * wgt, f3.y * wgt, f3.z * wgt, f3.w * wgt);
            row[4] = make_float4(f4.x * wgt, f4.y * wgt, f4.z * wgt, f4.w * wgt);
            row[5] = make_float4(f5.x * wgt, f5.y * wgt, f5.z * wgt, f5.w * wgt);
        }
    } else {
        // degenerate fallback: exact streaming top-64 over all 4096
        float Lv = INF; int Lm = 0x7FFFFFFF;
        for (int c = 0; c < 64; ++c) {
            int m = c * 64 + lane;
            float4 cm = c4[m];
            float s2 = fmaf(cm.x, cm.x, fmaf(cm.y, cm.y, fmaf(cm.z, cm.z, cm.w * cm.w)));
            float dt = fmaf(cqj.x, cm.x, fmaf(cqj.y, cm.y, fmaf(cqj.z, cm.z, cqj.w * cm.w)));
            float v  = fmaxf(fmaf(-2.f, dt, s2 + sqnj), 0.f);
            if (m == nj) v = INF;
            sort64_pair(v, m, lane);
            if (c == 0) { Lv = v; Lm = m; }
            else        merge64(Lv, Lm, v, m, lane);
        }
        if (lane < KSEL) {
            float wgt = __expf(-10.f * Lv);
            const float4* fr = (const float4*)(feats + ((size_t)b * NN + Lm) * PPAD);
            float4 f0 = fr[0], f1 = fr[1], f2 = fr[2], f3 = fr[3], f4 = fr[4], f5 = fr[5];
            float4* row = (float4*)(fstage + lane * PPAD);
            row[0] = make_float4(f0.x * wgt, f0.y * wgt, f0.z * wgt, f0.w * wgt);
            row[1] = make_float4(f1.x * wgt, f1.y * wgt, f1.z * wgt, f1.w * wgt);
            row[2] = make_float4(f2.x * wgt, f2.y * wgt, f2.z * wgt, f2.w * wgt);
            row[3] = make_float4(f3.x * wgt, f3.y * wgt, f3.z * wgt, f3.w * wgt);
            row[4] = make_float4(f4.x * wgt, f4.y * wgt, f4.z * wgt, f4.w * wgt);
            row[5] = make_float4(f5.x * wgt, f5.y * wgt, f5.z * wgt, f5.w * wgt);
        }
    }
    WSYNC();

    // ---- max / mean over 39 neighbors: 44 lanes, split-k ----
    if (lane < 2 * PP) {
        int g  = (lane >= PP) ? 1 : 0;
        int c  = lane - g * PP;
        int k0 = g ? 20 : 0;
        int k1 = g ? KSEL : 20;
        float mx = NEGINF, sm = 0.f;
        for (int k = k0; k < k1; ++k) {
            float v = fstage[k * PPAD + c];
            mx = fmaxf(mx, v);
            sm += v;
        }
        float mx2 = __shfl(mx, lane + PP);
        float sm2 = __shfl(sm, lane + PP);
        if (lane < PP) {
            agg[c]      = fmaxf(mx, mx2);
            agg[PP + c] = (sm + sm2) * (1.f / (float)KSEL);
        }
    }
    WSYNC();

    // ---- epilogue: out = tanh([x | max | mean] @ Wo + bo), fast tanh ----
    if (lane < FOUT) {
        const float* xr = x + (size_t)qj * FIN;
        float acc = bo[lane];
        #pragma unroll
        for (int f = 0; f < FIN; ++f)
            acc = fmaf(xr[f], Wo[f * FOUT + lane], acc);
        #pragma unroll
        for (int f = 0; f < 2 * PP; ++f)
            acc = fmaf(agg[f], Wo[(FIN + f) * FOUT + lane], acc);
        float e = __expf(2.f * acc);
        float r = __builtin_amdgcn_rcpf(e + 1.f);
        out[(size_t)qj * FOUT + lane] = fmaf(-2.f, r, 1.f);
    }
    WSYNC();
}

// ---------------- main: one wave per FOUR queries, f = h - q.m scans -------------
__global__ __launch_bounds__(WPB * 64, 8) void gn_main(
    const float* __restrict__ x,
    const float* __restrict__ Wo, const float* __restrict__ bo,
    const float* __restrict__ coords4, const float* __restrict__ harr,
    const float* __restrict__ feats,
    float* __restrict__ out)
{
    __shared__ unsigned short sel_s[WPB * QW * CAP];     // candidate indices
    __shared__ float fstage_s[WPB * KSEL * PPAD];
    __shared__ float agg_s[WPB * 48];
    __shared__ unsigned cnt_s[WPB * QW];
    __shared__ unsigned cnt2_s[WPB];

    const float INF = __builtin_inff();
    const int wv    = threadIdx.x >> 6;
    const int lane  = threadIdx.x & 63;
    const int qbase = (blockIdx.x * WPB + wv) * QW;      // 4 queries, same batch
    const int b     = qbase >> 12;
    const int n0    = qbase & (NN - 1);
    unsigned short* selp = sel_s + wv * QW * CAP;
    float* fstage = fstage_s + wv * (KSEL * PPAD);
    float* agg    = agg_s + wv * 48;

    const float4* c4 = ((const float4*)coords4) + (size_t)b * NN;
    const float*  hB = harr + (size_t)b * NN;

    // per-query constants -- individual scalars only
    float4 cq0 = c4[n0 + 0], cq1 = c4[n0 + 1], cq2 = c4[n0 + 2], cq3 = c4[n0 + 3];

    if (lane < QW) cnt_s[wv * QW + lane] = 0;

    // ---- pass 1: f = h - q.m per query, running min (self included) ----
    float km0 = INF, km1 = INF, km2 = INF, km3 = INF;
    #pragma unroll 4
    for (int i = 0; i < 64; ++i) {
        int m = i * 64 + lane;
        float4 cm = c4[m];
        float hm = hB[m];
        float f0 = fmaf(-cq0.x, cm.x, hm);
        f0 = fmaf(-cq0.y, cm.y, f0);
        f0 = fmaf(-cq0.z, cm.z, f0);
        f0 = fmaf(-cq0.w, cm.w, f0);
        float f1 = fmaf(-cq1.x, cm.x, hm);
        f1 = fmaf(-cq1.y, cm.y, f1);
        f1 = fmaf(-cq1.z, cm.z, f1);
        f1 = fmaf(-cq1.w, cm.w, f1);
        float f2 = fmaf(-cq2.x, cm.x, hm);
        f2 = fmaf(-cq2.y, cm.y, f2);
        f2 = fmaf(-cq2.z, cm.z, f2);
        f2 = fmaf(-cq2.w, cm.w, f2);
        float f3 = fmaf(-cq3.x, cm.x, hm);
        f3 = fmaf(-cq3.y, cm.y, f3);
        f3 = fmaf(-cq3.z, cm.z, f3);
        f3 = fmaf(-cq3.w, cm.w, f3);
        km0 = fminf(km0, f0);
        km1 = fminf(km1, f1);
        km2 = fminf(km2, f2);
        km3 = fminf(km3, f3);
    }
    unsigned kb0 = keyof(km0);
    unsigned kb1 = keyof(km1);
    unsigned kb2 = keyof(km2);
    unsigned kb3 = keyof(km3);

    // ---- bounds: 40th-smallest lane-min f-key, TRUNCATED radix (bits 31..15),
    //      widen low bits -> exact superset threshold in f-space.
    unsigned ub0 = 0, ub1 = 0, ub2 = 0, ub3 = 0;
    for (int bit = 31; bit >= 15; --bit) {
        unsigned msk = 1u << bit;
        unsigned t0 = ub0 | msk, t1 = ub1 | msk, t2 = ub2 | msk, t3 = ub3 | msk;
        if ((int)__popcll(__ballot(kb0 < t0)) < KSEL + 1) ub0 = t0;
        if ((int)__popcll(__ballot(kb1 < t1)) < KSEL + 1) ub1 = t1;
        if ((int)__popcll(__ballot(kb2 < t2)) < KSEL + 1) ub2 = t2;
        if ((int)__popcll(__ballot(kb3 < t3)) < KSEL + 1) ub3 = t3;
    }
    // NaN-region guard: cap widened key below keyof(+inf) = 0xFF800000
    float UB0 = keyinv(min(ub0 | 0x7FFFu, 0xFF7FFFFFu));
    float UB1 = keyinv(min(ub1 | 0x7FFFu, 0xFF7FFFFFu));
    float UB2 = keyinv(min(ub2 | 0x7FFFu, 0xFF7FFFFFu));
    float UB3 = keyinv(min(ub3 | 0x7FFFu, 0xFF7FFFFFu));
    WSYNC();   // cnt init visible

    // ---- compact pass: f <= UB, store idx to LDS ----
    #pragma unroll 4
    for (int i = 0; i < 64; ++i) {
        int m = i * 64 + lane;
        float4 cm = c4[m];
        float hm = hB[m];
        float f0 = fmaf(-cq0.x, cm.x, hm);
        f0 = fmaf(-cq0.y, cm.y, f0);
        f0 = fmaf(-cq0.z, cm.z, f0);
        f0 = fmaf(-cq0.w, cm.w, f0);
        float f1 = fmaf(-cq1.x, cm.x, hm);
        f1 = fmaf(-cq1.y, cm.y, f1);
        f1 = fmaf(-cq1.z, cm.z, f1);
        f1 = fmaf(-cq1.w, cm.w, f1);
        float f2 = fmaf(-cq2.x, cm.x, hm);
        f2 = fmaf(-cq2.y, cm.y, f2);
        f2 = fmaf(-cq2.z, cm.z, f2);
        f2 = fmaf(-cq2.w, cm.w, f2);
        float f3 = fmaf(-cq3.x, cm.x, hm);
        f3 = fmaf(-cq3.y, cm.y, f3);
        f3 = fmaf(-cq3.z, cm.z, f3);
        f3 = fmaf(-cq3.w, cm.w, f3);
        if ((f0 <= UB0) && (m != n0 + 0)) {
            unsigned s = atomicAdd(&cnt_s[wv * QW + 0], 1u);
            if (s < CAP) selp[0 * CAP + s] = (unsigned short)m;
        }
        if ((f1 <= UB1) && (m != n0 + 1)) {
            unsigned s = atomicAdd(&cnt_s[wv * QW + 1], 1u);
            if (s < CAP) selp[1 * CAP + s] = (unsigned short)m;
        }
        if ((f2 <= UB2) && (m != n0 + 2)) {
            unsigned s = atomicAdd(&cnt_s[wv * QW + 2], 1u);
            if (s < CAP) selp[2 * CAP + s] = (unsigned short)m;
        }
        if ((f3 <= UB3) && (m != n0 + 3)) {
            unsigned s = atomicAdd(&cnt_s[wv * QW + 3], 1u);
            if (s < CAP) selp[3 * CAP + s] = (unsigned short)m;
        }
    }
    WSYNC();

    // ---- four explicit tail calls (no runtime-indexed private state) ----
    tail_query(lane, b, n0 + 0, qbase + 0, (int)cnt_s[wv * QW + 0], selp + 0 * CAP,
               c4, feats, x, Wo, bo, fstage, agg, &cnt2_s[wv], out);
    tail_query(lane, b, n0 + 1, qbase + 1, (int)cnt_s[wv * QW + 1], selp + 1 * CAP,
               c4, feats, x, Wo, bo, fstage, agg, &cnt2_s[wv], out);
    tail_query(lane, b, n0 + 2, qbase + 2, (int)cnt_s[wv * QW + 2], selp + 2 * CAP,
               c4, feats, x, Wo, bo, fstage, agg, &cnt2_s[wv], out);
    tail_query(lane, b, n0 + 3, qbase + 3, (int)cnt_s[wv * QW + 3], selp + 3 * CAP,
               c4, feats, x, Wo, bo, fstage, agg, &cnt2_s[wv], out);
}

extern "C" void kernel_launch(void* const* d_in, const int* in_sizes, int n_in,
                              void* d_out, int out_size, void* d_ws, size_t ws_size,
                              hipStream_t stream) {
    const float* x  = (const float*)d_in[0];
    const float* Wf = (const float*)d_in[1];
    const float* bf = (const float*)d_in[2];
    const float* Ws = (const float*)d_in[3];
    const float* bs = (const float*)d_in[4];
    const float* Wo = (const float*)d_in[5];
    const float* bo = (const float*)d_in[6];
    float* outp = (float*)d_out;

    float* ws      = (float*)d_ws;
    float* coords4 = ws;                      // 32768*4  = 131072 floats
    float* harr    = ws + 131072;             // 32768 floats
    float* feats   = ws + 131072 + 32768;     // 32768*24 = 786432 floats

    gn_pre<<<32768 / 256, 256, 0, stream>>>(x, Wf, bf, Ws, bs, coords4, harr, feats);
    gn_main<<<32768 / (WPB * QW), WPB * 64, 0, stream>>>(x, Wo, bo, coords4, harr, feats, outp);
}